// Round 1
// baseline (518.594 us; speedup 1.0000x reference)
//
#include <hip/hip_runtime.h>

#define P_CNT 32768
#define D_DIM 256
#define B_SZ  256
#define INVT  20.0f          // 1/TEMP
#define NEG_BIG -3.0e38f

// ---------------- block reduction helpers (256 threads, wave64) ----------------
__device__ __forceinline__ float blockMax(float v, int tid, float* red4) {
#pragma unroll
  for (int off = 1; off < 64; off <<= 1) v = fmaxf(v, __shfl_xor(v, off));
  if ((tid & 63) == 0) red4[tid >> 6] = v;
  __syncthreads();
  float r = fmaxf(fmaxf(red4[0], red4[1]), fmaxf(red4[2], red4[3]));
  __syncthreads();
  return r;
}

__device__ __forceinline__ float blockSum(float v, int tid, float* red4) {
#pragma unroll
  for (int off = 1; off < 64; off <<= 1) v += __shfl_xor(v, off);
  if ((tid & 63) == 0) red4[tid >> 6] = v;
  __syncthreads();
  float r = red4[0] + red4[1] + red4[2] + red4[3];
  __syncthreads();
  return r;
}

// argmax with smaller-index tie-break (matches jax top_k / argmax)
__device__ __forceinline__ void blockArgmax(float& v, int& idx, int tid,
                                            float* red4, int* redi4) {
#pragma unroll
  for (int off = 1; off < 64; off <<= 1) {
    float v2 = __shfl_xor(v, off);
    int   i2 = __shfl_xor(idx, off);
    if (v2 > v || (v2 == v && i2 < idx)) { v = v2; idx = i2; }
  }
  if ((tid & 63) == 0) { red4[tid >> 6] = v; redi4[tid >> 6] = idx; }
  __syncthreads();
  v = red4[0]; idx = redi4[0];
#pragma unroll
  for (int w = 1; w < 4; ++w) {
    float v2 = red4[w]; int i2 = redi4[w];
    if (v2 > v || (v2 == v && i2 < idx)) { v = v2; idx = i2; }
  }
  __syncthreads();
}

// ---------------- kernel 0: gather prx, build A' = [features; mem[prx]] ----------------
__global__ void prep_kernel(const float* __restrict__ features,
                            const int* __restrict__ targets,
                            const int* __restrict__ all_prx,
                            const float* __restrict__ mem,
                            float* __restrict__ A2,
                            int* __restrict__ prxArr) {
  const int b = blockIdx.x;
  const int k = threadIdx.x;
  const int t = targets[b];
  const int pr = all_prx[t];
  if (k == 0) prxArr[b] = pr;
  A2[b * D_DIM + k] = features[b * D_DIM + k];
  A2[(B_SZ + b) * D_DIM + k] = mem[(size_t)pr * D_DIM + k];
}

// ---------------- kernel 1: f32 GEMM, OUT[r][p] = sum_k A'[r][k]*mem[p][k] ----------------
// A': [512][256] row-major, mem: [32768][256] row-major (NT gemm, both K-contiguous)
__global__ __launch_bounds__(256) void gemm_nt(const float* __restrict__ A,
                                               const float* __restrict__ Bm,
                                               float* __restrict__ Co) {
  __shared__ float As[32][64];
  __shared__ float Bs[32][64];
  const int tid = threadIdx.x;
  const int tx = tid & 15;
  const int ty = tid >> 4;
  const int rowBase = blockIdx.y << 6;
  const int colBase = blockIdx.x << 6;
  const int lr = tid >> 2;          // 0..63 : tile row to load
  const int lk = (tid & 3) << 3;    // 0,8,16,24 : k sub-offset
  float acc[4][4] = {};
  const float* Aptr = A + (size_t)(rowBase + lr) * D_DIM + lk;
  const float* Bptr = Bm + (size_t)(colBase + lr) * D_DIM + lk;
  for (int k0 = 0; k0 < D_DIM; k0 += 32) {
    float4 a0 = *(const float4*)(Aptr + k0);
    float4 a1 = *(const float4*)(Aptr + k0 + 4);
    float4 b0 = *(const float4*)(Bptr + k0);
    float4 b1 = *(const float4*)(Bptr + k0 + 4);
    __syncthreads();
    As[lk + 0][lr] = a0.x; As[lk + 1][lr] = a0.y; As[lk + 2][lr] = a0.z; As[lk + 3][lr] = a0.w;
    As[lk + 4][lr] = a1.x; As[lk + 5][lr] = a1.y; As[lk + 6][lr] = a1.z; As[lk + 7][lr] = a1.w;
    Bs[lk + 0][lr] = b0.x; Bs[lk + 1][lr] = b0.y; Bs[lk + 2][lr] = b0.z; Bs[lk + 3][lr] = b0.w;
    Bs[lk + 4][lr] = b1.x; Bs[lk + 5][lr] = b1.y; Bs[lk + 6][lr] = b1.z; Bs[lk + 7][lr] = b1.w;
    __syncthreads();
#pragma unroll
    for (int k = 0; k < 32; ++k) {
      float4 av = *(const float4*)&As[k][ty << 2];
      float4 bv = *(const float4*)&Bs[k][tx << 2];
      acc[0][0] += av.x * bv.x; acc[0][1] += av.x * bv.y; acc[0][2] += av.x * bv.z; acc[0][3] += av.x * bv.w;
      acc[1][0] += av.y * bv.x; acc[1][1] += av.y * bv.y; acc[1][2] += av.y * bv.z; acc[1][3] += av.y * bv.w;
      acc[2][0] += av.z * bv.x; acc[2][1] += av.z * bv.y; acc[2][2] += av.z * bv.z; acc[2][3] += av.z * bv.w;
      acc[3][0] += av.w * bv.x; acc[3][1] += av.w * bv.y; acc[3][2] += av.w * bv.z; acc[3][3] += av.w * bv.w;
    }
  }
#pragma unroll
  for (int i = 0; i < 4; ++i) {
    float4 o = make_float4(acc[i][0], acc[i][1], acc[i][2], acc[i][3]);
    *(float4*)(Co + (size_t)(rowBase + (ty << 2) + i) * P_CNT + colBase + (tx << 2)) = o;
  }
}

// ---------------- kernel 2: per-sample losses (one block per sample) ----------------
__global__ __launch_bounds__(256) void persample(const float* __restrict__ OUT,
                                                 const int* __restrict__ cams,
                                                 const int* __restrict__ prxArr,
                                                 float* __restrict__ intraArr,
                                                 float* __restrict__ crossArr,
                                                 float* __restrict__ onlArr) {
  __shared__ float row[P_CNT];      // 128 KiB: full score (then sims) row
  __shared__ float red4[4];
  __shared__ int   redi4[4];
  __shared__ float sv[64];
  __shared__ int   si[64];
  __shared__ float cv32[32];
  __shared__ int   ci32[32];

  const int b = blockIdx.x;
  const int tid = threadIdx.x;
  const float* Srow = OUT + (size_t)b * P_CNT;
  const float* Mrow = OUT + (size_t)(B_SZ + b) * P_CNT;
  const int pr = prxArr[b];
  const int cam = cams[b];
  float4* row4 = (float4*)row;

  // stage score row into LDS
  for (int i = tid; i < P_CNT / 4; i += 256) row4[i] = ((const float4*)Srow)[i];
  __syncthreads();

  // ---- intra: log_softmax over {p : p%8 == cam}, value at prx ----
  float m = NEG_BIG;
  for (int j = tid; j < P_CNT / 8; j += 256) m = fmaxf(m, row[cam + 8 * j]);
  m = blockMax(m, tid, red4);
  float s = 0.f;
  for (int j = tid; j < P_CNT / 8; j += 256) s += expf((row[cam + 8 * j] - m) * INVT);
  s = blockSum(s, tid, red4);
  if (tid == 0) intraArr[b] = -((row[pr] - m) * INVT - logf(s));
  __syncthreads();

  // ---- cross: pos = contiguous [pr&~7 .. +7]; top-50 of the rest ----
  const int posBase = pr & ~7;
  if (tid < 8) { sv[tid] = row[posBase + tid]; row[posBase + tid] = NEG_BIG; }
  __syncthreads();
  for (int it = 0; it < 50; ++it) {
    float bm = NEG_BIG; int bi = 0x7fffffff;
    for (int i = tid; i < P_CNT / 4; i += 256) {
      float4 v = row4[i]; int base = i << 2;
      if (v.x > bm) { bm = v.x; bi = base; }
      if (v.y > bm) { bm = v.y; bi = base + 1; }
      if (v.z > bm) { bm = v.z; bi = base + 2; }
      if (v.w > bm) { bm = v.w; bi = base + 3; }
    }
    blockArgmax(bm, bi, tid, red4, redi4);
    if (tid == 0) { sv[8 + it] = bm; si[8 + it] = bi; row[bi] = NEG_BIG; }
    __syncthreads();
  }
  if (tid == 0) {
    float mm = NEG_BIG;
    for (int k = 0; k < 58; ++k) mm = fmaxf(mm, sv[k]);
    float ss = 0.f;
    for (int k = 0; k < 58; ++k) ss += expf((sv[k] - mm) * INVT);
    float lse = logf(ss);
    float acc = 0.f;
    for (int k = 0; k < 8; ++k) acc += (sv[k] - mm) * INVT - lse;
    crossArr[b] = -acc * 0.125f;
  }
  __syncthreads();
  // restore row
  if (tid < 8) row[posBase + tid] = sv[tid];
  if (tid < 50) row[si[8 + tid]] = sv[8 + tid];
  __syncthreads();

  // ---- online: row := sims = 0.15*score + 0.85*memsim ----
  for (int i = tid; i < P_CNT / 4; i += 256) {
    float4 v = row4[i];
    float4 m2 = ((const float4*)Mrow)[i];
    v.x = 0.15f * v.x + 0.85f * m2.x;
    v.y = 0.15f * v.y + 0.85f * m2.y;
    v.z = 0.15f * v.z + 0.85f * m2.z;
    v.w = 0.15f * v.w + 0.85f * m2.w;
    row4[i] = v;
  }
  __syncthreads();

  // per-camera argmax: thread tid only sees p%8 == tid%8 (stride 256)
  {
    float bm = NEG_BIG; int bi = 0x7fffffff;
    for (int p = tid; p < P_CNT; p += 256) {
      float v = row[p];
      if (v > bm) { bm = v; bi = p; }
    }
#pragma unroll
    for (int off = 8; off <= 32; off <<= 1) {   // offsets preserve class mod 8
      float v2 = __shfl_xor(bm, off);
      int   i2 = __shfl_xor(bi, off);
      if (v2 > bm || (v2 == bm && i2 < bi)) { bm = v2; bi = i2; }
    }
    int lane = tid & 63;
    if (lane < 8) { cv32[(tid >> 6) * 8 + lane] = bm; ci32[(tid >> 6) * 8 + lane] = bi; }
    __syncthreads();
    if (tid < 8) {
      float v = cv32[tid]; int ix = ci32[tid];
      for (int w = 1; w < 4; ++w) {
        float v2 = cv32[w * 8 + tid]; int i2 = ci32[w * 8 + tid];
        if (v2 > v || (v2 == v && i2 < ix)) { v = v2; ix = i2; }
      }
      cv32[tid] = v; ci32[tid] = ix;
    }
    __syncthreads();
    if (tid == 0) {
      unsigned used = 0;
      for (int k = 0; k < 3; ++k) {      // top-3 cameras by best-proxy sim
        float best = NEG_BIG; int bc = 0;
        for (int c = 0; c < 8; ++c)
          if (!((used >> c) & 1u) && cv32[c] > best) { best = cv32[c]; bc = c; }
        used |= 1u << bc;
        si[k] = ci32[bc];
        row[ci32[bc]] = NEG_BIG;
      }
    }
    __syncthreads();
  }
  // top-50 of remaining sims (indices only; values gathered from score)
  for (int it = 0; it < 50; ++it) {
    float bm = NEG_BIG; int bi = 0x7fffffff;
    for (int i = tid; i < P_CNT / 4; i += 256) {
      float4 v = row4[i]; int base = i << 2;
      if (v.x > bm) { bm = v.x; bi = base; }
      if (v.y > bm) { bm = v.y; bi = base + 1; }
      if (v.z > bm) { bm = v.z; bi = base + 2; }
      if (v.w > bm) { bm = v.w; bi = base + 3; }
    }
    blockArgmax(bm, bi, tid, red4, redi4);
    if (tid == 0) { si[3 + it] = bi; row[bi] = NEG_BIG; }
    __syncthreads();
  }
  if (tid < 53) sv[tid] = Srow[si[tid]];   // gather inputs (score) at selected indices
  __syncthreads();
  if (tid == 0) {
    float mm = NEG_BIG;
    for (int k = 0; k < 53; ++k) mm = fmaxf(mm, sv[k]);
    float ss = 0.f;
    for (int k = 0; k < 53; ++k) ss += expf((sv[k] - mm) * INVT);
    float lse = logf(ss);
    float acc = 0.f;
    for (int k = 0; k < 3; ++k) acc += (sv[k] - mm) * INVT - lse;
    onlArr[b] = -acc * (1.0f / 3.0f);
  }
}

// ---------------- kernel 3: per-camera means -> scalar ----------------
__global__ void finalize(const int* __restrict__ cams,
                         const float* __restrict__ ia,
                         const float* __restrict__ ca,
                         const float* __restrict__ oa,
                         float* __restrict__ out) {
  if (blockIdx.x == 0 && threadIdx.x == 0) {
    float s[8] = {}; float n[8] = {};
    for (int b = 0; b < B_SZ; ++b) {
      int c = cams[b];
      s[c] += ia[b] + ca[b] + oa[b];
      n[c] += 1.f;
    }
    float tot = 0.f;
    for (int c = 0; c < 8; ++c)
      if (n[c] > 0.f) tot += s[c] / n[c];
    out[0] = tot;
  }
}

extern "C" void kernel_launch(void* const* d_in, const int* in_sizes, int n_in,
                              void* d_out, int out_size, void* d_ws, size_t ws_size,
                              hipStream_t stream) {
  const float* features = (const float*)d_in[0];
  const int*   targets  = (const int*)d_in[1];
  const int*   cams     = (const int*)d_in[2];
  // d_in[3] = epoch (unused)
  const float* mem      = (const float*)d_in[4];
  // d_in[5] = all_pseudo_label (pos derived from prx instead)
  const int*   all_prx  = (const int*)d_in[6];
  // d_in[7] = cam_proxies, d_in[8] = label_proxies (structure known analytically)

  float* ws = (float*)d_ws;
  float* A2  = ws;                               // 512*256
  float* OUT = ws + 512 * D_DIM;                 // 512*32768
  float* tail = OUT + (size_t)512 * P_CNT;
  int*   prxArr  = (int*)tail;                   // 256
  float* intraArr = (float*)(prxArr + B_SZ);     // 256
  float* crossArr = intraArr + B_SZ;             // 256
  float* onlArr   = crossArr + B_SZ;             // 256

  prep_kernel<<<B_SZ, D_DIM, 0, stream>>>(features, targets, all_prx, mem, A2, prxArr);
  dim3 g1(P_CNT / 64, 512 / 64);
  gemm_nt<<<g1, 256, 0, stream>>>(A2, mem, OUT);
  persample<<<B_SZ, 256, 0, stream>>>(OUT, cams, prxArr, intraArr, crossArr, onlArr);
  finalize<<<1, 64, 0, stream>>>(cams, intraArr, crossArr, onlArr, (float*)d_out);
}

// Round 2
// 339.552 us; speedup vs baseline: 1.5273x; 1.5273x over previous
//
#include <hip/hip_runtime.h>

#define P_CNT 32768
#define D_DIM 256
#define B_SZ  256
#define INVT  20.0f          // 1/TEMP
#define NEG_BIG -3.0e38f

// ---------------- block reduction helpers (256 threads, wave64) ----------------
__device__ __forceinline__ float blockMax(float v, int tid, float* red4) {
#pragma unroll
  for (int off = 1; off < 64; off <<= 1) v = fmaxf(v, __shfl_xor(v, off));
  if ((tid & 63) == 0) red4[tid >> 6] = v;
  __syncthreads();
  float r = fmaxf(fmaxf(red4[0], red4[1]), fmaxf(red4[2], red4[3]));
  __syncthreads();
  return r;
}

__device__ __forceinline__ float blockSum(float v, int tid, float* red4) {
#pragma unroll
  for (int off = 1; off < 64; off <<= 1) v += __shfl_xor(v, off);
  if ((tid & 63) == 0) red4[tid >> 6] = v;
  __syncthreads();
  float r = red4[0] + red4[1] + red4[2] + red4[3];
  __syncthreads();
  return r;
}

// argmax with smaller-index tie-break (matches jax top_k / argmax)
__device__ __forceinline__ void blockArgmax(float& v, int& idx, int tid,
                                            float* red4, int* redi4) {
#pragma unroll
  for (int off = 1; off < 64; off <<= 1) {
    float v2 = __shfl_xor(v, off);
    int   i2 = __shfl_xor(idx, off);
    if (v2 > v || (v2 == v && i2 < idx)) { v = v2; idx = i2; }
  }
  if ((tid & 63) == 0) { red4[tid >> 6] = v; redi4[tid >> 6] = idx; }
  __syncthreads();
  v = red4[0]; idx = redi4[0];
#pragma unroll
  for (int w = 1; w < 4; ++w) {
    float v2 = red4[w]; int i2 = redi4[w];
    if (v2 > v || (v2 == v && i2 < idx)) { v = v2; idx = i2; }
  }
  __syncthreads();
}

// Build tournament: L1[j] = max(row[16j..16j+16)), j in [0,2048).
// Returns this thread's L2 value = max(L1[8*tid .. 8*tid+8)) (= leaves [128*tid,128*tid+128)).
__device__ __forceinline__ float buildL1(const float* row, float* L1, int tid) {
  const float4* row4 = (const float4*)row;
#pragma unroll
  for (int w = 0; w < 8; ++w) {
    int j = tid + 256 * w;           // strided build: 2-way bank alias only
    float4 a = row4[4 * j + 0];
    float4 b = row4[4 * j + 1];
    float4 c = row4[4 * j + 2];
    float4 d = row4[4 * j + 3];
    float m = fmaxf(fmaxf(fmaxf(a.x, a.y), fmaxf(a.z, a.w)),
                    fmaxf(fmaxf(b.x, b.y), fmaxf(b.z, b.w)));
    m = fmaxf(m, fmaxf(fmaxf(fmaxf(c.x, c.y), fmaxf(c.z, c.w)),
                       fmaxf(fmaxf(d.x, d.y), fmaxf(d.z, d.w))));
    L1[j] = m;
  }
  __syncthreads();
  float mv = NEG_BIG;
#pragma unroll
  for (int k = 0; k < 8; ++k) mv = fmaxf(mv, L1[8 * tid + k]);
  return mv;
}

// Extract top-niter by value (smallest-index tie-break), recording values+indices.
__device__ __forceinline__ void extractTopK(float* row, float* L1, float& myv,
                                            int tid, int niter,
                                            float* sv, int* si, int base,
                                            float* red4, int* redi4) {
  for (int it = 0; it < niter; ++it) {
    float v = myv; int u = tid;
    blockArgmax(v, u, tid, red4, redi4);
    if (tid == u) {
      int jf = 8 * u;
      for (int j = 8 * u; j < 8 * u + 8; ++j) {
        if (L1[j] == v) { jf = j; break; }
      }
      int leaf = 16 * jf;
      for (int l = 16 * jf; l < 16 * jf + 16; ++l) {
        if (row[l] == v) { leaf = l; break; }
      }
      sv[base + it] = v; si[base + it] = leaf;
      row[leaf] = NEG_BIG;
      float m1 = NEG_BIG;
      for (int l = 16 * jf; l < 16 * jf + 16; ++l) m1 = fmaxf(m1, row[l]);
      L1[jf] = m1;
      float m2 = NEG_BIG;
      for (int j = 8 * u; j < 8 * u + 8; ++j) m2 = fmaxf(m2, L1[j]);
      myv = m2;
    }
    __syncthreads();
  }
}

// ---------------- kernel 0: gather prx, build A' = [features; mem[prx]] ----------------
__global__ void prep_kernel(const float* __restrict__ features,
                            const int* __restrict__ targets,
                            const int* __restrict__ all_prx,
                            const float* __restrict__ mem,
                            float* __restrict__ A2,
                            int* __restrict__ prxArr) {
  const int b = blockIdx.x;
  const int k = threadIdx.x;
  const int t = targets[b];
  const int pr = all_prx[t];
  if (k == 0) prxArr[b] = pr;
  A2[b * D_DIM + k] = features[b * D_DIM + k];
  A2[(B_SZ + b) * D_DIM + k] = mem[(size_t)pr * D_DIM + k];
}

// ---------------- kernel 1: f32 GEMM, OUT[r][p] = sum_k A'[r][k]*mem[p][k] ----------------
__global__ __launch_bounds__(256) void gemm_nt(const float* __restrict__ A,
                                               const float* __restrict__ Bm,
                                               float* __restrict__ Co) {
  __shared__ float As[32][64];
  __shared__ float Bs[32][64];
  const int tid = threadIdx.x;
  const int tx = tid & 15;
  const int ty = tid >> 4;
  const int rowBase = blockIdx.y << 6;
  const int colBase = blockIdx.x << 6;
  const int lr = tid >> 2;          // 0..63 : tile row to load
  const int lk = (tid & 3) << 3;    // 0,8,16,24 : k sub-offset
  float acc[4][4] = {};
  const float* Aptr = A + (size_t)(rowBase + lr) * D_DIM + lk;
  const float* Bptr = Bm + (size_t)(colBase + lr) * D_DIM + lk;
  for (int k0 = 0; k0 < D_DIM; k0 += 32) {
    float4 a0 = *(const float4*)(Aptr + k0);
    float4 a1 = *(const float4*)(Aptr + k0 + 4);
    float4 b0 = *(const float4*)(Bptr + k0);
    float4 b1 = *(const float4*)(Bptr + k0 + 4);
    __syncthreads();
    As[lk + 0][lr] = a0.x; As[lk + 1][lr] = a0.y; As[lk + 2][lr] = a0.z; As[lk + 3][lr] = a0.w;
    As[lk + 4][lr] = a1.x; As[lk + 5][lr] = a1.y; As[lk + 6][lr] = a1.z; As[lk + 7][lr] = a1.w;
    Bs[lk + 0][lr] = b0.x; Bs[lk + 1][lr] = b0.y; Bs[lk + 2][lr] = b0.z; Bs[lk + 3][lr] = b0.w;
    Bs[lk + 4][lr] = b1.x; Bs[lk + 5][lr] = b1.y; Bs[lk + 6][lr] = b1.z; Bs[lk + 7][lr] = b1.w;
    __syncthreads();
#pragma unroll
    for (int k = 0; k < 32; ++k) {
      float4 av = *(const float4*)&As[k][ty << 2];
      float4 bv = *(const float4*)&Bs[k][tx << 2];
      acc[0][0] += av.x * bv.x; acc[0][1] += av.x * bv.y; acc[0][2] += av.x * bv.z; acc[0][3] += av.x * bv.w;
      acc[1][0] += av.y * bv.x; acc[1][1] += av.y * bv.y; acc[1][2] += av.y * bv.z; acc[1][3] += av.y * bv.w;
      acc[2][0] += av.z * bv.x; acc[2][1] += av.z * bv.y; acc[2][2] += av.z * bv.z; acc[2][3] += av.z * bv.w;
      acc[3][0] += av.w * bv.x; acc[3][1] += av.w * bv.y; acc[3][2] += av.w * bv.z; acc[3][3] += av.w * bv.w;
    }
  }
#pragma unroll
  for (int i = 0; i < 4; ++i) {
    float4 o = make_float4(acc[i][0], acc[i][1], acc[i][2], acc[i][3]);
    *(float4*)(Co + (size_t)(rowBase + (ty << 2) + i) * P_CNT + colBase + (tx << 2)) = o;
  }
}

// ---------------- kernel 2: per-sample losses (one block per sample) ----------------
__global__ __launch_bounds__(256) void persample(const float* __restrict__ OUT,
                                                 const int* __restrict__ cams,
                                                 const int* __restrict__ prxArr,
                                                 float* __restrict__ intraArr,
                                                 float* __restrict__ crossArr,
                                                 float* __restrict__ onlArr) {
  __shared__ float row[P_CNT];      // 128 KiB: score row, then sims row
  __shared__ float L1[2048];        // 8 KiB tournament level-1
  __shared__ float red4[4];
  __shared__ int   redi4[4];
  __shared__ float sv[64];
  __shared__ int   si[64];
  __shared__ float cv32[32];
  __shared__ int   ci32[32];

  const int b = blockIdx.x;
  const int tid = threadIdx.x;
  const float* Srow = OUT + (size_t)b * P_CNT;
  const float* Mrow = OUT + (size_t)(B_SZ + b) * P_CNT;
  const int pr = prxArr[b];
  const int cam = cams[b];
  float4* row4 = (float4*)row;

  // stage score row into LDS
  for (int i = tid; i < P_CNT / 4; i += 256) row4[i] = ((const float4*)Srow)[i];
  __syncthreads();

  // ---- intra: log_softmax over {p : p%8 == cam}, value at prx ----
  float m = NEG_BIG;
  for (int j = tid; j < P_CNT / 8; j += 256) m = fmaxf(m, row[cam + 8 * j]);
  m = blockMax(m, tid, red4);
  float s = 0.f;
  for (int j = tid; j < P_CNT / 8; j += 256) s += expf((row[cam + 8 * j] - m) * INVT);
  s = blockSum(s, tid, red4);
  if (tid == 0) intraArr[b] = -((row[pr] - m) * INVT - logf(s));
  __syncthreads();

  // ---- cross: pos = contiguous [pr&~7 .. +7]; top-50 of the rest via tournament ----
  const int posBase = pr & ~7;
  if (tid < 8) { sv[tid] = row[posBase + tid]; row[posBase + tid] = NEG_BIG; }
  __syncthreads();
  {
    float myv = buildL1(row, L1, tid);
    __syncthreads();
    extractTopK(row, L1, myv, tid, 50, sv, si, 8, red4, redi4);
  }
  // LSE over 58 values, weight 1/8 on first 8 — single wave
  if (tid < 64) {
    float v = (tid < 58) ? sv[tid] : NEG_BIG;
    float mm = v;
#pragma unroll
    for (int off = 1; off < 64; off <<= 1) mm = fmaxf(mm, __shfl_xor(mm, off));
    float e = (tid < 58) ? expf((v - mm) * INVT) : 0.f;
    float ss = e;
#pragma unroll
    for (int off = 1; off < 64; off <<= 1) ss += __shfl_xor(ss, off);
    float lse = logf(ss);
    float c = (tid < 8) ? ((v - mm) * INVT - lse) : 0.f;
#pragma unroll
    for (int off = 1; off < 64; off <<= 1) c += __shfl_xor(c, off);
    if (tid == 0) crossArr[b] = -c * 0.125f;
  }
  __syncthreads();

  // ---- online: row := sims = 0.15*score + 0.85*memsim (re-read score from global, L2-hot) ----
  for (int i = tid; i < P_CNT / 4; i += 256) {
    float4 v = ((const float4*)Srow)[i];
    float4 m2 = ((const float4*)Mrow)[i];
    v.x = 0.15f * v.x + 0.85f * m2.x;
    v.y = 0.15f * v.y + 0.85f * m2.y;
    v.z = 0.15f * v.z + 0.85f * m2.z;
    v.w = 0.15f * v.w + 0.85f * m2.w;
    row4[i] = v;
  }
  __syncthreads();

  // per-camera argmax over sims: thread tid sees p%8 == tid%8 (stride 256, conflict-free)
  {
    float bm = NEG_BIG; int bi = 0x7fffffff;
    for (int p = tid; p < P_CNT; p += 256) {
      float v = row[p];
      if (v > bm) { bm = v; bi = p; }
    }
#pragma unroll
    for (int off = 8; off <= 32; off <<= 1) {   // offsets preserve class mod 8
      float v2 = __shfl_xor(bm, off);
      int   i2 = __shfl_xor(bi, off);
      if (v2 > bm || (v2 == bm && i2 < bi)) { bm = v2; bi = i2; }
    }
    int lane = tid & 63;
    if (lane < 8) { cv32[(tid >> 6) * 8 + lane] = bm; ci32[(tid >> 6) * 8 + lane] = bi; }
    __syncthreads();
    if (tid < 8) {
      float v = cv32[tid]; int ix = ci32[tid];
      for (int w = 1; w < 4; ++w) {
        float v2 = cv32[w * 8 + tid]; int i2 = ci32[w * 8 + tid];
        if (v2 > v || (v2 == v && i2 < ix)) { v = v2; ix = i2; }
      }
      cv32[tid] = v; ci32[tid] = ix;
    }
    __syncthreads();
    if (tid == 0) {
      unsigned used = 0;
      for (int k = 0; k < 3; ++k) {      // top-3 cameras by best-proxy sim
        float best = NEG_BIG; int bc = 0;
        for (int c = 0; c < 8; ++c)
          if (!((used >> c) & 1u) && cv32[c] > best) { best = cv32[c]; bc = c; }
        used |= 1u << bc;
        si[k] = ci32[bc];
        row[ci32[bc]] = NEG_BIG;
      }
    }
    __syncthreads();
  }
  // top-50 of remaining sims via tournament (indices only; values gathered from score)
  {
    float myv = buildL1(row, L1, tid);
    __syncthreads();
    extractTopK(row, L1, myv, tid, 50, sv, si, 3, red4, redi4);
  }
  if (tid < 53) sv[tid] = Srow[si[tid]];   // gather score at selected indices
  __syncthreads();
  if (tid < 64) {
    float v = (tid < 53) ? sv[tid] : NEG_BIG;
    float mm = v;
#pragma unroll
    for (int off = 1; off < 64; off <<= 1) mm = fmaxf(mm, __shfl_xor(mm, off));
    float e = (tid < 53) ? expf((v - mm) * INVT) : 0.f;
    float ss = e;
#pragma unroll
    for (int off = 1; off < 64; off <<= 1) ss += __shfl_xor(ss, off);
    float lse = logf(ss);
    float c = (tid < 3) ? ((v - mm) * INVT - lse) : 0.f;
#pragma unroll
    for (int off = 1; off < 64; off <<= 1) c += __shfl_xor(c, off);
    if (tid == 0) onlArr[b] = -c * (1.0f / 3.0f);
  }
}

// ---------------- kernel 3: per-camera means -> scalar ----------------
__global__ void finalize(const int* __restrict__ cams,
                         const float* __restrict__ ia,
                         const float* __restrict__ ca,
                         const float* __restrict__ oa,
                         float* __restrict__ out) {
  if (blockIdx.x == 0 && threadIdx.x == 0) {
    float s[8] = {}; float n[8] = {};
    for (int b = 0; b < B_SZ; ++b) {
      int c = cams[b];
      s[c] += ia[b] + ca[b] + oa[b];
      n[c] += 1.f;
    }
    float tot = 0.f;
    for (int c = 0; c < 8; ++c)
      if (n[c] > 0.f) tot += s[c] / n[c];
    out[0] = tot;
  }
}

extern "C" void kernel_launch(void* const* d_in, const int* in_sizes, int n_in,
                              void* d_out, int out_size, void* d_ws, size_t ws_size,
                              hipStream_t stream) {
  const float* features = (const float*)d_in[0];
  const int*   targets  = (const int*)d_in[1];
  const int*   cams     = (const int*)d_in[2];
  const float* mem      = (const float*)d_in[4];
  const int*   all_prx  = (const int*)d_in[6];

  float* ws = (float*)d_ws;
  float* A2  = ws;                               // 512*256
  float* OUT = ws + 512 * D_DIM;                 // 512*32768
  float* tail = OUT + (size_t)512 * P_CNT;
  int*   prxArr  = (int*)tail;                   // 256
  float* intraArr = (float*)(prxArr + B_SZ);     // 256
  float* crossArr = intraArr + B_SZ;             // 256
  float* onlArr   = crossArr + B_SZ;             // 256

  prep_kernel<<<B_SZ, D_DIM, 0, stream>>>(features, targets, all_prx, mem, A2, prxArr);
  dim3 g1(P_CNT / 64, 512 / 64);
  gemm_nt<<<g1, 256, 0, stream>>>(A2, mem, OUT);
  persample<<<B_SZ, 256, 0, stream>>>(OUT, cams, prxArr, intraArr, crossArr, onlArr);
  finalize<<<1, 64, 0, stream>>>(cams, intraArr, crossArr, onlArr, (float*)d_out);
}

// Round 3
// 315.594 us; speedup vs baseline: 1.6432x; 1.0759x over previous
//
#include <hip/hip_runtime.h>

#define P_CNT 32768
#define D_DIM 256
#define B_SZ  256
#define INVT  20.0f          // 1/TEMP
#define NEG_BIG -3.0e38f

// ---------------- block reduction helpers (256 threads, wave64) ----------------
__device__ __forceinline__ float blockMax(float v, int tid, float* red4) {
#pragma unroll
  for (int off = 1; off < 64; off <<= 1) v = fmaxf(v, __shfl_xor(v, off));
  if ((tid & 63) == 0) red4[tid >> 6] = v;
  __syncthreads();
  float r = fmaxf(fmaxf(red4[0], red4[1]), fmaxf(red4[2], red4[3]));
  __syncthreads();
  return r;
}

__device__ __forceinline__ float blockSum(float v, int tid, float* red4) {
#pragma unroll
  for (int off = 1; off < 64; off <<= 1) v += __shfl_xor(v, off);
  if ((tid & 63) == 0) red4[tid >> 6] = v;
  __syncthreads();
  float r = red4[0] + red4[1] + red4[2] + red4[3];
  __syncthreads();
  return r;
}

// ---------------- exact k-th largest via 4-bit radix select ----------------
// row: LDS floats (holes = NEG_BIG). Returns exact k-th largest value.
// Integer radix bookkeeping => no fp bin-edge inconsistencies; fully parallel.
__device__ float radixSelectK(const float* __restrict__ row, int k, int tid,
                              int* histW /*64*/, float* bufV /*64*/,
                              int* cntS, float* bcast) {
  const uint4* rowU = (const uint4*)row;
  const int lane = tid & 63, wid = tid >> 6;
  unsigned prefix = 0;
  int krem = k;
  int shift = 28;
  for (;;) {
    unsigned long long accLo = 0ull, accHi = 0ull;
    const int sh4 = shift + 4;
    for (int i = tid; i < P_CNT / 4; i += 256) {
      uint4 q = rowU[i];
#pragma unroll
      for (int c = 0; c < 4; ++c) {
        unsigned b = (c == 0) ? q.x : (c == 1) ? q.y : (c == 2) ? q.z : q.w;
        unsigned key = b ^ ((unsigned)(((int)b) >> 31) | 0x80000000u);
        bool ok = (sh4 >= 32) || ((key >> sh4) == prefix);
        int bin = (key >> shift) & 15;
        unsigned long long one = ok ? 1ull : 0ull;
        if (bin < 8) accLo += one << (bin << 3);
        else         accHi += one << ((bin - 8) << 3);
      }
    }
    int cnt[16];
#pragma unroll
    for (int j = 0; j < 8; ++j) cnt[j] = (int)((accLo >> (j * 8)) & 0xffull);
#pragma unroll
    for (int j = 0; j < 8; ++j) cnt[8 + j] = (int)((accHi >> (j * 8)) & 0xffull);
#pragma unroll
    for (int j = 0; j < 16; ++j) {
      int v = cnt[j];
#pragma unroll
      for (int off = 1; off < 64; off <<= 1) v += __shfl_xor(v, off);
      cnt[j] = v;
    }
    if (lane == 0) {
#pragma unroll
      for (int j = 0; j < 16; ++j) histW[wid * 16 + j] = cnt[j];
    }
    __syncthreads();
    int tot[16];
#pragma unroll
    for (int j = 0; j < 16; ++j)
      tot[j] = histW[j] + histW[16 + j] + histW[32 + j] + histW[48 + j];
    __syncthreads();  // histW reusable next pass
    int t = -1, above = 0;
#pragma unroll
    for (int j = 15; j >= 0; --j) {
      if (t < 0) {
        if (above + tot[j] >= krem) t = j;
        else above += tot[j];
      }
    }
    krem -= above;                 // rank within bin t
    prefix = (prefix << 4) | (unsigned)t;
    int cntT = tot[t];
    if (cntT <= 64 || shift == 0) break;
    shift -= 4;
  }
  // collect candidates of the final bin (exact key-prefix match)
  if (tid == 0) cntS[0] = 0;
  __syncthreads();
  for (int i = tid; i < P_CNT; i += 256) {
    float v = row[i];
    unsigned b = __float_as_uint(v);
    unsigned key = b ^ ((unsigned)(((int)b) >> 31) | 0x80000000u);
    if ((key >> shift) == prefix) {
      int p = atomicAdd(cntS, 1);
      if (p < 64) bufV[p] = v;
    }
  }
  __syncthreads();
  if (tid < 64) {
    int n = min(cntS[0], 64);
    float vl = (tid < n) ? bufV[tid] : NEG_BIG;
    float vk = NEG_BIG;
    for (int it = 0; it < krem; ++it) {
      float wv = vl;
#pragma unroll
      for (int off = 1; off < 64; off <<= 1) wv = fmaxf(wv, __shfl_xor(wv, off));
      if (it == krem - 1) vk = wv;
      unsigned long long m = __ballot(vl == wv);
      int fl = (int)__ffsll(m) - 1;
      if (tid == fl) vl = NEG_BIG;      // remove exactly one instance
    }
    if (tid == 0) bcast[0] = vk;
  }
  __syncthreads();
  float r = bcast[0];
  __syncthreads();
  return r;
}

// ---------------- kernel 0: gather prx, build A' = [features; mem[prx]] ----------------
__global__ void prep_kernel(const float* __restrict__ features,
                            const int* __restrict__ targets,
                            const int* __restrict__ all_prx,
                            const float* __restrict__ mem,
                            float* __restrict__ A2,
                            int* __restrict__ prxArr) {
  const int b = blockIdx.x;
  const int k = threadIdx.x;
  const int t = targets[b];
  const int pr = all_prx[t];
  if (k == 0) prxArr[b] = pr;
  A2[b * D_DIM + k] = features[b * D_DIM + k];
  A2[(B_SZ + b) * D_DIM + k] = mem[(size_t)pr * D_DIM + k];
}

// ---------------- kernel 1: f32 GEMM, OUT[r][p] = sum_k A'[r][k]*mem[p][k] ----------------
__global__ __launch_bounds__(256) void gemm_nt(const float* __restrict__ A,
                                               const float* __restrict__ Bm,
                                               float* __restrict__ Co) {
  __shared__ float As[32][64];
  __shared__ float Bs[32][64];
  const int tid = threadIdx.x;
  const int tx = tid & 15;
  const int ty = tid >> 4;
  const int rowBase = blockIdx.y << 6;
  const int colBase = blockIdx.x << 6;
  const int lr = tid >> 2;
  const int lk = (tid & 3) << 3;
  float acc[4][4] = {};
  const float* Aptr = A + (size_t)(rowBase + lr) * D_DIM + lk;
  const float* Bptr = Bm + (size_t)(colBase + lr) * D_DIM + lk;
  for (int k0 = 0; k0 < D_DIM; k0 += 32) {
    float4 a0 = *(const float4*)(Aptr + k0);
    float4 a1 = *(const float4*)(Aptr + k0 + 4);
    float4 b0 = *(const float4*)(Bptr + k0);
    float4 b1 = *(const float4*)(Bptr + k0 + 4);
    __syncthreads();
    As[lk + 0][lr] = a0.x; As[lk + 1][lr] = a0.y; As[lk + 2][lr] = a0.z; As[lk + 3][lr] = a0.w;
    As[lk + 4][lr] = a1.x; As[lk + 5][lr] = a1.y; As[lk + 6][lr] = a1.z; As[lk + 7][lr] = a1.w;
    Bs[lk + 0][lr] = b0.x; Bs[lk + 1][lr] = b0.y; Bs[lk + 2][lr] = b0.z; Bs[lk + 3][lr] = b0.w;
    Bs[lk + 4][lr] = b1.x; Bs[lk + 5][lr] = b1.y; Bs[lk + 6][lr] = b1.z; Bs[lk + 7][lr] = b1.w;
    __syncthreads();
#pragma unroll
    for (int k = 0; k < 32; ++k) {
      float4 av = *(const float4*)&As[k][ty << 2];
      float4 bv = *(const float4*)&Bs[k][tx << 2];
      acc[0][0] += av.x * bv.x; acc[0][1] += av.x * bv.y; acc[0][2] += av.x * bv.z; acc[0][3] += av.x * bv.w;
      acc[1][0] += av.y * bv.x; acc[1][1] += av.y * bv.y; acc[1][2] += av.y * bv.z; acc[1][3] += av.y * bv.w;
      acc[2][0] += av.z * bv.x; acc[2][1] += av.z * bv.y; acc[2][2] += av.z * bv.z; acc[2][3] += av.z * bv.w;
      acc[3][0] += av.w * bv.x; acc[3][1] += av.w * bv.y; acc[3][2] += av.w * bv.z; acc[3][3] += av.w * bv.w;
    }
  }
#pragma unroll
  for (int i = 0; i < 4; ++i) {
    float4 o = make_float4(acc[i][0], acc[i][1], acc[i][2], acc[i][3]);
    *(float4*)(Co + (size_t)(rowBase + (ty << 2) + i) * P_CNT + colBase + (tx << 2)) = o;
  }
}

// ---------------- kernel 2: per-sample losses (one block per sample) ----------------
__global__ __launch_bounds__(256) void persample(const float* __restrict__ OUT,
                                                 const int* __restrict__ cams,
                                                 const int* __restrict__ prxArr,
                                                 float* __restrict__ intraArr,
                                                 float* __restrict__ crossArr,
                                                 float* __restrict__ onlArr) {
  __shared__ float row[P_CNT];      // 128 KiB: score row, then sims row
  __shared__ int   histW[64];
  __shared__ float bufV[64];
  __shared__ int   bufI[32];
  __shared__ int   cntS[4];
  __shared__ float red4[4];
  __shared__ float sv[64];
  __shared__ int   si[64];
  __shared__ float cv32[32];
  __shared__ int   ci32[32];
  __shared__ float mw[4], sw[4];
  __shared__ float bcast[2];

  const int b = blockIdx.x;
  const int tid = threadIdx.x;
  const int lane = tid & 63, wid = tid >> 6;
  const float* Srow = OUT + (size_t)b * P_CNT;
  const float* Mrow = OUT + (size_t)(B_SZ + b) * P_CNT;
  const int pr = prxArr[b];
  const int cam = cams[b];
  float4* row4 = (float4*)row;
  const int camHi = cam >> 2, camLo = cam & 3;

  // ---- stage score row into LDS; fold in row-max and intra online-LSE ----
  float pmax = NEG_BIG;
  float im = NEG_BIG, is = 0.f;     // intra online logsumexp state
  for (int i = tid; i < P_CNT / 4; i += 256) {
    float4 q = ((const float4*)Srow)[i];
    row4[i] = q;
    pmax = fmaxf(fmaxf(fmaxf(q.x, q.y), fmaxf(q.z, q.w)), pmax);
    if ((i & 1) == camHi) {         // this float4 holds residue `cam`
      float v = (camLo == 0) ? q.x : (camLo == 1) ? q.y : (camLo == 2) ? q.z : q.w;
      if (v <= im) is += expf((v - im) * INVT);
      else { is = is * expf((im - v) * INVT) + 1.f; im = v; }
    }
  }
  __syncthreads();
  const float M = blockMax(pmax, tid, red4);   // exact max of score row

  // intra merge: wave shuffle LSE-merge, then 4 waves via LDS
#pragma unroll
  for (int off = 1; off < 64; off <<= 1) {
    float m2 = __shfl_xor(im, off);
    float s2 = __shfl_xor(is, off);
    float Mx = fmaxf(im, m2);
    is = is * expf((im - Mx) * INVT) + s2 * expf((m2 - Mx) * INVT);
    im = Mx;
  }
  if (lane == 0) { mw[wid] = im; sw[wid] = is; }
  __syncthreads();
  if (tid == 0) {
    float m0 = mw[0], s0 = sw[0];
    for (int w = 1; w < 4; ++w) {
      float Mx = fmaxf(m0, mw[w]);
      s0 = s0 * expf((m0 - Mx) * INVT) + sw[w] * expf((mw[w] - Mx) * INVT);
      m0 = Mx;
    }
    intraArr[b] = -((row[pr] - m0) * INVT - logf(s0));
  }
  __syncthreads();

  // ---- cross: pos = [pr&~7 .. +7]; exact 50th of the rest via radix select ----
  const int posBase = pr & ~7;
  if (tid < 8) { sv[tid] = row[posBase + tid]; row[posBase + tid] = NEG_BIG; }
  __syncthreads();
  const float vk = radixSelectK(row, 50, tid, histW, bufV, cntS, bcast);
  // exp-sum over the exact top-50 set (strictly-greater + multiplicity at vk)
  {
    float se = 0.f, cg = 0.f;
    for (int i = tid; i < P_CNT / 4; i += 256) {
      float4 q = row4[i];
      if (q.x > vk) { se += expf((q.x - M) * INVT); cg += 1.f; }
      if (q.y > vk) { se += expf((q.y - M) * INVT); cg += 1.f; }
      if (q.z > vk) { se += expf((q.z - M) * INVT); cg += 1.f; }
      if (q.w > vk) { se += expf((q.w - M) * INVT); cg += 1.f; }
    }
    se = blockSum(se, tid, red4);
    cg = blockSum(cg, tid, red4);
    if (tid == 0) {
      float stot = se + (50.f - cg) * expf((vk - M) * INVT);
      for (int p = 0; p < 8; ++p) stot += expf((sv[p] - M) * INVT);
      float lse = logf(stot);
      float acc = 0.f;
      for (int p = 0; p < 8; ++p) acc += (sv[p] - M) * INVT - lse;
      crossArr[b] = -acc * 0.125f;
    }
  }
  // restore pos values (row reused as score source for sims)
  if (tid < 8) row[posBase + tid] = sv[tid];
  __syncthreads();

  // ---- online: row := sims = 0.15*score + 0.85*memsim ----
  for (int i = tid; i < P_CNT / 4; i += 256) {
    float4 v = row4[i];
    float4 m2 = ((const float4*)Mrow)[i];
    v.x = 0.15f * v.x + 0.85f * m2.x;
    v.y = 0.15f * v.y + 0.85f * m2.y;
    v.z = 0.15f * v.z + 0.85f * m2.z;
    v.w = 0.15f * v.w + 0.85f * m2.w;
    row4[i] = v;
  }
  __syncthreads();

  // per-camera argmax over sims: thread tid sees p%8 == tid%8 (conflict-free)
  {
    float bm = NEG_BIG; int bi = 0x7fffffff;
    for (int p = tid; p < P_CNT; p += 256) {
      float v = row[p];
      if (v > bm) { bm = v; bi = p; }
    }
#pragma unroll
    for (int off = 8; off <= 32; off <<= 1) {   // offsets preserve class mod 8
      float v2 = __shfl_xor(bm, off);
      int   i2 = __shfl_xor(bi, off);
      if (v2 > bm || (v2 == bm && i2 < bi)) { bm = v2; bi = i2; }
    }
    if (lane < 8) { cv32[wid * 8 + lane] = bm; ci32[wid * 8 + lane] = bi; }
    __syncthreads();
    if (tid < 8) {
      float v = cv32[tid]; int ix = ci32[tid];
      for (int w = 1; w < 4; ++w) {
        float v2 = cv32[w * 8 + tid]; int i2 = ci32[w * 8 + tid];
        if (v2 > v || (v2 == v && i2 < ix)) { v = v2; ix = i2; }
      }
      cv32[tid] = v; ci32[tid] = ix;
    }
    __syncthreads();
    if (tid == 0) {
      unsigned used = 0;
      for (int k = 0; k < 3; ++k) {      // top-3 cameras by best-proxy sim
        float best = NEG_BIG; int bc = 0;
        for (int c = 0; c < 8; ++c)
          if (!((used >> c) & 1u) && cv32[c] > best) { best = cv32[c]; bc = c; }
        used |= 1u << bc;
        si[k] = ci32[bc];
        row[ci32[bc]] = NEG_BIG;
      }
    }
    __syncthreads();
  }

  // exact 50th of remaining sims; collect indices (greater + smallest-index equals)
  const float vk2 = radixSelectK(row, 50, tid, histW, bufV, cntS, bcast);
  if (tid == 0) { cntS[1] = 0; cntS[2] = 0; }
  __syncthreads();
  for (int i = tid; i < P_CNT; i += 256) {
    float v = row[i];
    if (v > vk2) {
      int p = atomicAdd(&cntS[1], 1);
      if (p < 50) si[3 + p] = i;
    } else if (v == vk2) {
      int p = atomicAdd(&cntS[2], 1);
      if (p < 32) bufI[p] = i;
    }
  }
  __syncthreads();
  {
    const int cg = cntS[1];          // ≤ 49 by definition of 50th largest
    const int fill = 50 - cg;
    if (tid < 64) {
      int ne = min(cntS[2], 32);
      int il = (tid < ne) ? bufI[tid] : 0x7fffffff;
      for (int it = 0; it < fill; ++it) {
        int wi = il;
#pragma unroll
        for (int off = 1; off < 64; off <<= 1) wi = min(wi, __shfl_xor(wi, off));
        if (tid == 0) si[3 + cg + it] = wi;
        if (il == wi) il = 0x7fffffff;
      }
    }
  }
  __syncthreads();
  if (tid < 53) sv[tid] = Srow[si[tid]];   // gather scores at selected indices
  __syncthreads();
  if (tid < 64) {
    float v = (tid < 53) ? sv[tid] : NEG_BIG;
    float mm = v;
#pragma unroll
    for (int off = 1; off < 64; off <<= 1) mm = fmaxf(mm, __shfl_xor(mm, off));
    float e = (tid < 53) ? expf((v - mm) * INVT) : 0.f;
    float ss = e;
#pragma unroll
    for (int off = 1; off < 64; off <<= 1) ss += __shfl_xor(ss, off);
    float lse = logf(ss);
    float c = (tid < 3) ? ((v - mm) * INVT - lse) : 0.f;
#pragma unroll
    for (int off = 1; off < 64; off <<= 1) c += __shfl_xor(c, off);
    if (tid == 0) onlArr[b] = -c * (1.0f / 3.0f);
  }
}

// ---------------- kernel 3: per-camera means -> scalar ----------------
__global__ void finalize(const int* __restrict__ cams,
                         const float* __restrict__ ia,
                         const float* __restrict__ ca,
                         const float* __restrict__ oa,
                         float* __restrict__ out) {
  if (blockIdx.x == 0 && threadIdx.x == 0) {
    float s[8] = {}; float n[8] = {};
    for (int b = 0; b < B_SZ; ++b) {
      int c = cams[b];
      s[c] += ia[b] + ca[b] + oa[b];
      n[c] += 1.f;
    }
    float tot = 0.f;
    for (int c = 0; c < 8; ++c)
      if (n[c] > 0.f) tot += s[c] / n[c];
    out[0] = tot;
  }
}

extern "C" void kernel_launch(void* const* d_in, const int* in_sizes, int n_in,
                              void* d_out, int out_size, void* d_ws, size_t ws_size,
                              hipStream_t stream) {
  const float* features = (const float*)d_in[0];
  const int*   targets  = (const int*)d_in[1];
  const int*   cams     = (const int*)d_in[2];
  const float* mem      = (const float*)d_in[4];
  const int*   all_prx  = (const int*)d_in[6];

  float* ws = (float*)d_ws;
  float* A2  = ws;                               // 512*256
  float* OUT = ws + 512 * D_DIM;                 // 512*32768
  float* tail = OUT + (size_t)512 * P_CNT;
  int*   prxArr  = (int*)tail;                   // 256
  float* intraArr = (float*)(prxArr + B_SZ);     // 256
  float* crossArr = intraArr + B_SZ;             // 256
  float* onlArr   = crossArr + B_SZ;             // 256

  prep_kernel<<<B_SZ, D_DIM, 0, stream>>>(features, targets, all_prx, mem, A2, prxArr);
  dim3 g1(P_CNT / 64, 512 / 64);
  gemm_nt<<<g1, 256, 0, stream>>>(A2, mem, OUT);
  persample<<<B_SZ, 256, 0, stream>>>(OUT, cams, prxArr, intraArr, crossArr, onlArr);
  finalize<<<1, 64, 0, stream>>>(cams, intraArr, crossArr, onlArr, (float*)d_out);
}

// Round 4
// 261.516 us; speedup vs baseline: 1.9830x; 1.2068x over previous
//
#include <hip/hip_runtime.h>

#define P_CNT 32768
#define D_DIM 256
#define B_SZ  256
#define NTHR  1024
#define NW    16
#define INVT  20.0f          // 1/TEMP
#define NEG_BIG -3.0e38f

// ---------------- block reduction helpers (1024 threads, wave64) ----------------
__device__ __forceinline__ float blockMax(float v, int tid, float* redW) {
#pragma unroll
  for (int off = 1; off < 64; off <<= 1) v = fmaxf(v, __shfl_xor(v, off));
  if ((tid & 63) == 0) redW[tid >> 6] = v;
  __syncthreads();
  float r = redW[0];
#pragma unroll
  for (int w = 1; w < NW; ++w) r = fmaxf(r, redW[w]);
  __syncthreads();
  return r;
}

__device__ __forceinline__ float blockSum(float v, int tid, float* redW) {
#pragma unroll
  for (int off = 1; off < 64; off <<= 1) v += __shfl_xor(v, off);
  if ((tid & 63) == 0) redW[tid >> 6] = v;
  __syncthreads();
  float r = 0.f;
#pragma unroll
  for (int w = 0; w < NW; ++w) r += redW[w];
  __syncthreads();
  return r;
}

// ---------------- exact k-th largest via 4-bit radix select ----------------
// row: LDS floats (holes = NEG_BIG). Returns exact k-th largest value.
__device__ float radixSelectK(const float* __restrict__ row, int k, int tid,
                              int* histW /*NW*16*/, int* histT /*16*/,
                              float* bufV /*64*/, int* cntS, float* bcast) {
  const uint4* rowU = (const uint4*)row;
  const int lane = tid & 63, wid = tid >> 6;
  unsigned prefix = 0;
  int krem = k;
  int shift = 28;
  for (;;) {
    unsigned long long accLo = 0ull, accHi = 0ull;
    const int sh4 = shift + 4;
    for (int i = tid; i < P_CNT / 4; i += NTHR) {
      uint4 q = rowU[i];
#pragma unroll
      for (int c = 0; c < 4; ++c) {
        unsigned b = (c == 0) ? q.x : (c == 1) ? q.y : (c == 2) ? q.z : q.w;
        unsigned key = b ^ ((unsigned)(((int)b) >> 31) | 0x80000000u);
        bool ok = (sh4 >= 32) || ((key >> sh4) == prefix);
        int bin = (key >> shift) & 15;
        unsigned long long one = ok ? 1ull : 0ull;
        if (bin < 8) accLo += one << (bin << 3);
        else         accHi += one << ((bin - 8) << 3);
      }
    }
    int cnt[16];
#pragma unroll
    for (int j = 0; j < 8; ++j) cnt[j] = (int)((accLo >> (j * 8)) & 0xffull);
#pragma unroll
    for (int j = 0; j < 8; ++j) cnt[8 + j] = (int)((accHi >> (j * 8)) & 0xffull);
#pragma unroll
    for (int j = 0; j < 16; ++j) {
      int v = cnt[j];
#pragma unroll
      for (int off = 1; off < 64; off <<= 1) v += __shfl_xor(v, off);
      cnt[j] = v;
    }
    if (lane == 0) {
#pragma unroll
      for (int j = 0; j < 16; ++j) histW[wid * 16 + j] = cnt[j];
    }
    __syncthreads();
    if (tid < 16) {
      int s = 0;
#pragma unroll
      for (int w = 0; w < NW; ++w) s += histW[w * 16 + tid];
      histT[tid] = s;
    }
    __syncthreads();
    int t = -1, above = 0, cntT = 0;
#pragma unroll
    for (int j = 15; j >= 0; --j) {
      int tj = histT[j];
      if (t < 0) {
        if (above + tj >= krem) { t = j; cntT = tj; }
        else above += tj;
      }
    }
    krem -= above;
    prefix = (prefix << 4) | (unsigned)t;
    if (cntT <= 64 || shift == 0) break;
    shift -= 4;
  }
  // collect candidates of the final bin (exact key-prefix match)
  if (tid == 0) cntS[0] = 0;
  __syncthreads();
  for (int i = tid; i < P_CNT; i += NTHR) {
    float v = row[i];
    unsigned b = __float_as_uint(v);
    unsigned key = b ^ ((unsigned)(((int)b) >> 31) | 0x80000000u);
    if ((key >> shift) == prefix) {
      int p = atomicAdd(cntS, 1);
      if (p < 64) bufV[p] = v;
    }
  }
  __syncthreads();
  if (tid < 64) {
    int n = min(cntS[0], 64);
    float vl = (tid < n) ? bufV[tid] : NEG_BIG;
    float vk = NEG_BIG;
    for (int it = 0; it < krem; ++it) {
      float wv = vl;
#pragma unroll
      for (int off = 1; off < 64; off <<= 1) wv = fmaxf(wv, __shfl_xor(wv, off));
      if (it == krem - 1) vk = wv;
      unsigned long long m = __ballot(vl == wv);
      int fl = (int)__ffsll(m) - 1;
      if (tid == fl) vl = NEG_BIG;
    }
    if (tid == 0) bcast[0] = vk;
  }
  __syncthreads();
  float r = bcast[0];
  __syncthreads();
  return r;
}

// ---------------- kernel 0: gather prx, build A' = [features; mem[prx]] ----------------
__global__ void prep_kernel(const float* __restrict__ features,
                            const int* __restrict__ targets,
                            const int* __restrict__ all_prx,
                            const float* __restrict__ mem,
                            float* __restrict__ A2,
                            int* __restrict__ prxArr) {
  const int b = blockIdx.x;
  const int k = threadIdx.x;
  const int t = targets[b];
  const int pr = all_prx[t];
  if (k == 0) prxArr[b] = pr;
  A2[b * D_DIM + k] = features[b * D_DIM + k];
  A2[(B_SZ + b) * D_DIM + k] = mem[(size_t)pr * D_DIM + k];
}

// ---------------- kernel 1: f32 GEMM, OUT[r][p] = sum_k A'[r][k]*mem[p][k] ----------------
__global__ __launch_bounds__(256) void gemm_nt(const float* __restrict__ A,
                                               const float* __restrict__ Bm,
                                               float* __restrict__ Co) {
  __shared__ float As[32][64];
  __shared__ float Bs[32][64];
  const int tid = threadIdx.x;
  const int tx = tid & 15;
  const int ty = tid >> 4;
  const int rowBase = blockIdx.y << 6;
  const int colBase = blockIdx.x << 6;
  const int lr = tid >> 2;
  const int lk = (tid & 3) << 3;
  float acc[4][4] = {};
  const float* Aptr = A + (size_t)(rowBase + lr) * D_DIM + lk;
  const float* Bptr = Bm + (size_t)(colBase + lr) * D_DIM + lk;
  for (int k0 = 0; k0 < D_DIM; k0 += 32) {
    float4 a0 = *(const float4*)(Aptr + k0);
    float4 a1 = *(const float4*)(Aptr + k0 + 4);
    float4 b0 = *(const float4*)(Bptr + k0);
    float4 b1 = *(const float4*)(Bptr + k0 + 4);
    __syncthreads();
    As[lk + 0][lr] = a0.x; As[lk + 1][lr] = a0.y; As[lk + 2][lr] = a0.z; As[lk + 3][lr] = a0.w;
    As[lk + 4][lr] = a1.x; As[lk + 5][lr] = a1.y; As[lk + 6][lr] = a1.z; As[lk + 7][lr] = a1.w;
    Bs[lk + 0][lr] = b0.x; Bs[lk + 1][lr] = b0.y; Bs[lk + 2][lr] = b0.z; Bs[lk + 3][lr] = b0.w;
    Bs[lk + 4][lr] = b1.x; Bs[lk + 5][lr] = b1.y; Bs[lk + 6][lr] = b1.z; Bs[lk + 7][lr] = b1.w;
    __syncthreads();
#pragma unroll
    for (int k = 0; k < 32; ++k) {
      float4 av = *(const float4*)&As[k][ty << 2];
      float4 bv = *(const float4*)&Bs[k][tx << 2];
      acc[0][0] += av.x * bv.x; acc[0][1] += av.x * bv.y; acc[0][2] += av.x * bv.z; acc[0][3] += av.x * bv.w;
      acc[1][0] += av.y * bv.x; acc[1][1] += av.y * bv.y; acc[1][2] += av.y * bv.z; acc[1][3] += av.y * bv.w;
      acc[2][0] += av.z * bv.x; acc[2][1] += av.z * bv.y; acc[2][2] += av.z * bv.z; acc[2][3] += av.z * bv.w;
      acc[3][0] += av.w * bv.x; acc[3][1] += av.w * bv.y; acc[3][2] += av.w * bv.z; acc[3][3] += av.w * bv.w;
    }
  }
#pragma unroll
  for (int i = 0; i < 4; ++i) {
    float4 o = make_float4(acc[i][0], acc[i][1], acc[i][2], acc[i][3]);
    *(float4*)(Co + (size_t)(rowBase + (ty << 2) + i) * P_CNT + colBase + (tx << 2)) = o;
  }
}

// ---------------- kernel 2: per-sample losses (one 1024-thread block per sample) ----------------
__global__ __launch_bounds__(NTHR) void persample(const float* __restrict__ OUT,
                                                  const int* __restrict__ cams,
                                                  const int* __restrict__ prxArr,
                                                  float* __restrict__ intraArr,
                                                  float* __restrict__ crossArr,
                                                  float* __restrict__ onlArr) {
  __shared__ float row[P_CNT];      // 128 KiB: score row, then sims row
  __shared__ int   histW[NW * 16];
  __shared__ int   histT[16];
  __shared__ float bufV[64];
  __shared__ int   bufI[32];
  __shared__ int   cntS[4];
  __shared__ float redW[NW];
  __shared__ float sv[64];
  __shared__ int   si[64];
  __shared__ float cvW[NW * 8];
  __shared__ int   ciW[NW * 8];
  __shared__ float mw[NW], sw[NW];
  __shared__ float bcast[2];

  const int b = blockIdx.x;
  const int tid = threadIdx.x;
  const int lane = tid & 63, wid = tid >> 6;
  const float* Srow = OUT + (size_t)b * P_CNT;
  const float* Mrow = OUT + (size_t)(B_SZ + b) * P_CNT;
  const int pr = prxArr[b];
  const int cam = cams[b];
  float4* row4 = (float4*)row;
  const int camHi = cam >> 2, camLo = cam & 3;

  // ---- stage score row into LDS; fold in row-max and intra online-LSE ----
  float pmax = NEG_BIG;
  float im = NEG_BIG, is = 0.f;
  for (int i = tid; i < P_CNT / 4; i += NTHR) {
    float4 q = ((const float4*)Srow)[i];
    row4[i] = q;
    pmax = fmaxf(fmaxf(fmaxf(q.x, q.y), fmaxf(q.z, q.w)), pmax);
    if ((i & 1) == camHi) {
      float v = (camLo == 0) ? q.x : (camLo == 1) ? q.y : (camLo == 2) ? q.z : q.w;
      if (v <= im) is += expf((v - im) * INVT);
      else { is = is * expf((im - v) * INVT) + 1.f; im = v; }
    }
  }
  __syncthreads();
  const float M = blockMax(pmax, tid, redW);

  // intra merge: wave shuffle LSE-merge, then NW waves via LDS
#pragma unroll
  for (int off = 1; off < 64; off <<= 1) {
    float m2 = __shfl_xor(im, off);
    float s2 = __shfl_xor(is, off);
    float Mx = fmaxf(im, m2);
    is = is * expf((im - Mx) * INVT) + s2 * expf((m2 - Mx) * INVT);
    im = Mx;
  }
  if (lane == 0) { mw[wid] = im; sw[wid] = is; }
  __syncthreads();
  if (tid == 0) {
    float m0 = mw[0], s0 = sw[0];
    for (int w = 1; w < NW; ++w) {
      float Mx = fmaxf(m0, mw[w]);
      s0 = s0 * expf((m0 - Mx) * INVT) + sw[w] * expf((mw[w] - Mx) * INVT);
      m0 = Mx;
    }
    intraArr[b] = -((row[pr] - m0) * INVT - logf(s0));
  }
  __syncthreads();

  // ---- cross: pos = [pr&~7 .. +7]; exact 50th of the rest via radix select ----
  const int posBase = pr & ~7;
  if (tid < 8) { sv[tid] = row[posBase + tid]; row[posBase + tid] = NEG_BIG; }
  __syncthreads();
  const float vk = radixSelectK(row, 50, tid, histW, histT, bufV, cntS, bcast);
  {
    float se = 0.f, cg = 0.f;
    for (int i = tid; i < P_CNT / 4; i += NTHR) {
      float4 q = row4[i];
      if (q.x > vk) { se += expf((q.x - M) * INVT); cg += 1.f; }
      if (q.y > vk) { se += expf((q.y - M) * INVT); cg += 1.f; }
      if (q.z > vk) { se += expf((q.z - M) * INVT); cg += 1.f; }
      if (q.w > vk) { se += expf((q.w - M) * INVT); cg += 1.f; }
    }
    se = blockSum(se, tid, redW);
    cg = blockSum(cg, tid, redW);
    if (tid == 0) {
      float stot = se + (50.f - cg) * expf((vk - M) * INVT);
      for (int p = 0; p < 8; ++p) stot += expf((sv[p] - M) * INVT);
      float lse = logf(stot);
      float acc = 0.f;
      for (int p = 0; p < 8; ++p) acc += (sv[p] - M) * INVT - lse;
      crossArr[b] = -acc * 0.125f;
    }
  }
  if (tid < 8) row[posBase + tid] = sv[tid];
  __syncthreads();

  // ---- online: row := sims = 0.15*score + 0.85*memsim ----
  for (int i = tid; i < P_CNT / 4; i += NTHR) {
    float4 v = row4[i];
    float4 m2 = ((const float4*)Mrow)[i];
    v.x = 0.15f * v.x + 0.85f * m2.x;
    v.y = 0.15f * v.y + 0.85f * m2.y;
    v.z = 0.15f * v.z + 0.85f * m2.z;
    v.w = 0.15f * v.w + 0.85f * m2.w;
    row4[i] = v;
  }
  __syncthreads();

  // per-camera argmax over sims: thread tid sees p%8 == tid%8 (conflict-free)
  {
    float bm = NEG_BIG; int bi = 0x7fffffff;
    for (int p = tid; p < P_CNT; p += NTHR) {
      float v = row[p];
      if (v > bm) { bm = v; bi = p; }
    }
#pragma unroll
    for (int off = 8; off <= 32; off <<= 1) {
      float v2 = __shfl_xor(bm, off);
      int   i2 = __shfl_xor(bi, off);
      if (v2 > bm || (v2 == bm && i2 < bi)) { bm = v2; bi = i2; }
    }
    if (lane < 8) { cvW[wid * 8 + lane] = bm; ciW[wid * 8 + lane] = bi; }
    __syncthreads();
    if (tid < 8) {
      float v = cvW[tid]; int ix = ciW[tid];
      for (int w = 1; w < NW; ++w) {
        float v2 = cvW[w * 8 + tid]; int i2 = ciW[w * 8 + tid];
        if (v2 > v || (v2 == v && i2 < ix)) { v = v2; ix = i2; }
      }
      cvW[tid] = v; ciW[tid] = ix;
    }
    __syncthreads();
    if (tid == 0) {
      unsigned used = 0;
      for (int k = 0; k < 3; ++k) {
        float best = NEG_BIG; int bc = 0;
        for (int c = 0; c < 8; ++c)
          if (!((used >> c) & 1u) && cvW[c] > best) { best = cvW[c]; bc = c; }
        used |= 1u << bc;
        si[k] = ciW[bc];
        row[ciW[bc]] = NEG_BIG;
      }
    }
    __syncthreads();
  }

  // exact 50th of remaining sims; collect indices (greater + smallest-index equals)
  const float vk2 = radixSelectK(row, 50, tid, histW, histT, bufV, cntS, bcast);
  if (tid == 0) { cntS[1] = 0; cntS[2] = 0; }
  __syncthreads();
  for (int i = tid; i < P_CNT; i += NTHR) {
    float v = row[i];
    if (v > vk2) {
      int p = atomicAdd(&cntS[1], 1);
      if (p < 50) si[3 + p] = i;
    } else if (v == vk2) {
      int p = atomicAdd(&cntS[2], 1);
      if (p < 32) bufI[p] = i;
    }
  }
  __syncthreads();
  {
    const int cg = cntS[1];
    const int fill = 50 - cg;
    if (tid < 64) {
      int ne = min(cntS[2], 32);
      int il = (tid < ne) ? bufI[tid] : 0x7fffffff;
      for (int it = 0; it < fill; ++it) {
        int wi = il;
#pragma unroll
        for (int off = 1; off < 64; off <<= 1) wi = min(wi, __shfl_xor(wi, off));
        if (tid == 0) si[3 + cg + it] = wi;
        if (il == wi) il = 0x7fffffff;
      }
    }
  }
  __syncthreads();
  if (tid < 53) sv[tid] = Srow[si[tid]];
  __syncthreads();
  if (tid < 64) {
    float v = (tid < 53) ? sv[tid] : NEG_BIG;
    float mm = v;
#pragma unroll
    for (int off = 1; off < 64; off <<= 1) mm = fmaxf(mm, __shfl_xor(mm, off));
    float e = (tid < 53) ? expf((v - mm) * INVT) : 0.f;
    float ss = e;
#pragma unroll
    for (int off = 1; off < 64; off <<= 1) ss += __shfl_xor(ss, off);
    float lse = logf(ss);
    float c = (tid < 3) ? ((v - mm) * INVT - lse) : 0.f;
#pragma unroll
    for (int off = 1; off < 64; off <<= 1) c += __shfl_xor(c, off);
    if (tid == 0) onlArr[b] = -c * (1.0f / 3.0f);
  }
}

// ---------------- kernel 3: per-camera means -> scalar ----------------
__global__ void finalize(const int* __restrict__ cams,
                         const float* __restrict__ ia,
                         const float* __restrict__ ca,
                         const float* __restrict__ oa,
                         float* __restrict__ out) {
  if (blockIdx.x == 0 && threadIdx.x == 0) {
    float s[8] = {}; float n[8] = {};
    for (int b = 0; b < B_SZ; ++b) {
      int c = cams[b];
      s[c] += ia[b] + ca[b] + oa[b];
      n[c] += 1.f;
    }
    float tot = 0.f;
    for (int c = 0; c < 8; ++c)
      if (n[c] > 0.f) tot += s[c] / n[c];
    out[0] = tot;
  }
}

extern "C" void kernel_launch(void* const* d_in, const int* in_sizes, int n_in,
                              void* d_out, int out_size, void* d_ws, size_t ws_size,
                              hipStream_t stream) {
  const float* features = (const float*)d_in[0];
  const int*   targets  = (const int*)d_in[1];
  const int*   cams     = (const int*)d_in[2];
  const float* mem      = (const float*)d_in[4];
  const int*   all_prx  = (const int*)d_in[6];

  float* ws = (float*)d_ws;
  float* A2  = ws;                               // 512*256
  float* OUT = ws + 512 * D_DIM;                 // 512*32768
  float* tail = OUT + (size_t)512 * P_CNT;
  int*   prxArr  = (int*)tail;                   // 256
  float* intraArr = (float*)(prxArr + B_SZ);     // 256
  float* crossArr = intraArr + B_SZ;             // 256
  float* onlArr   = crossArr + B_SZ;             // 256

  prep_kernel<<<B_SZ, D_DIM, 0, stream>>>(features, targets, all_prx, mem, A2, prxArr);
  dim3 g1(P_CNT / 64, 512 / 64);
  gemm_nt<<<g1, 256, 0, stream>>>(A2, mem, OUT);
  persample<<<B_SZ, NTHR, 0, stream>>>(OUT, cams, prxArr, intraArr, crossArr, onlArr);
  finalize<<<1, 64, 0, stream>>>(cams, intraArr, crossArr, onlArr, (float*)d_out);
}

// Round 5
// 180.166 us; speedup vs baseline: 2.8784x; 1.4515x over previous
//
#include <hip/hip_runtime.h>

#define P_CNT 32768
#define D_DIM 256
#define B_SZ  256
#define NTHR  1024
#define NW    16
#define INVT  20.0f          // 1/TEMP
#define NEG_BIG -3.0e38f

typedef _Float16 half8  __attribute__((ext_vector_type(8)));
typedef _Float16 half4v __attribute__((ext_vector_type(4)));
typedef float    floatx4 __attribute__((ext_vector_type(4)));

// ---------------- block reduction helpers (1024 threads, wave64) ----------------
__device__ __forceinline__ float blockMax(float v, int tid, float* redW) {
#pragma unroll
  for (int off = 1; off < 64; off <<= 1) v = fmaxf(v, __shfl_xor(v, off));
  if ((tid & 63) == 0) redW[tid >> 6] = v;
  __syncthreads();
  float r = redW[0];
#pragma unroll
  for (int w = 1; w < NW; ++w) r = fmaxf(r, redW[w]);
  __syncthreads();
  return r;
}

__device__ __forceinline__ float blockSum(float v, int tid, float* redW) {
#pragma unroll
  for (int off = 1; off < 64; off <<= 1) v += __shfl_xor(v, off);
  if ((tid & 63) == 0) redW[tid >> 6] = v;
  __syncthreads();
  float r = 0.f;
#pragma unroll
  for (int w = 0; w < NW; ++w) r += redW[w];
  __syncthreads();
  return r;
}

// ---------------- exact k-th largest via 4-bit radix select ----------------
__device__ float radixSelectK(const float* __restrict__ row, int k, int tid,
                              int* histW /*NW*16*/, int* histT /*16*/,
                              float* bufV /*64*/, int* cntS, float* bcast) {
  const uint4* rowU = (const uint4*)row;
  const int lane = tid & 63, wid = tid >> 6;
  unsigned prefix = 0;
  int krem = k;
  int shift = 28;
  for (;;) {
    unsigned long long accLo = 0ull, accHi = 0ull;
    const int sh4 = shift + 4;
    for (int i = tid; i < P_CNT / 4; i += NTHR) {
      uint4 q = rowU[i];
#pragma unroll
      for (int c = 0; c < 4; ++c) {
        unsigned b = (c == 0) ? q.x : (c == 1) ? q.y : (c == 2) ? q.z : q.w;
        unsigned key = b ^ ((unsigned)(((int)b) >> 31) | 0x80000000u);
        bool ok = (sh4 >= 32) || ((key >> sh4) == prefix);
        int bin = (key >> shift) & 15;
        unsigned long long one = ok ? 1ull : 0ull;
        if (bin < 8) accLo += one << (bin << 3);
        else         accHi += one << ((bin - 8) << 3);
      }
    }
    int cnt[16];
#pragma unroll
    for (int j = 0; j < 8; ++j) cnt[j] = (int)((accLo >> (j * 8)) & 0xffull);
#pragma unroll
    for (int j = 0; j < 8; ++j) cnt[8 + j] = (int)((accHi >> (j * 8)) & 0xffull);
#pragma unroll
    for (int j = 0; j < 16; ++j) {
      int v = cnt[j];
#pragma unroll
      for (int off = 1; off < 64; off <<= 1) v += __shfl_xor(v, off);
      cnt[j] = v;
    }
    if (lane == 0) {
#pragma unroll
      for (int j = 0; j < 16; ++j) histW[wid * 16 + j] = cnt[j];
    }
    __syncthreads();
    if (tid < 16) {
      int s = 0;
#pragma unroll
      for (int w = 0; w < NW; ++w) s += histW[w * 16 + tid];
      histT[tid] = s;
    }
    __syncthreads();
    int t = -1, above = 0, cntT = 0;
#pragma unroll
    for (int j = 15; j >= 0; --j) {
      int tj = histT[j];
      if (t < 0) {
        if (above + tj >= krem) { t = j; cntT = tj; }
        else above += tj;
      }
    }
    krem -= above;
    prefix = (prefix << 4) | (unsigned)t;
    if (cntT <= 64 || shift == 0) break;
    shift -= 4;
  }
  if (tid == 0) cntS[0] = 0;
  __syncthreads();
  for (int i = tid; i < P_CNT; i += NTHR) {
    float v = row[i];
    unsigned b = __float_as_uint(v);
    unsigned key = b ^ ((unsigned)(((int)b) >> 31) | 0x80000000u);
    if ((key >> shift) == prefix) {
      int p = atomicAdd(cntS, 1);
      if (p < 64) bufV[p] = v;
    }
  }
  __syncthreads();
  if (tid < 64) {
    int n = min(cntS[0], 64);
    float vl = (tid < n) ? bufV[tid] : NEG_BIG;
    float vk = NEG_BIG;
    for (int it = 0; it < krem; ++it) {
      float wv = vl;
#pragma unroll
      for (int off = 1; off < 64; off <<= 1) wv = fmaxf(wv, __shfl_xor(wv, off));
      if (it == krem - 1) vk = wv;
      unsigned long long m = __ballot(vl == wv);
      int fl = (int)__ffsll(m) - 1;
      if (tid == fl) vl = NEG_BIG;
    }
    if (tid == 0) bcast[0] = vk;
  }
  __syncthreads();
  float r = bcast[0];
  __syncthreads();
  return r;
}

// ---------------- kernel 0: gather prx, build A' = [features; mem[prx]] ----------------
__global__ void prep_kernel(const float* __restrict__ features,
                            const int* __restrict__ targets,
                            const int* __restrict__ all_prx,
                            const float* __restrict__ mem,
                            float* __restrict__ A2,
                            int* __restrict__ prxArr) {
  const int b = blockIdx.x;
  const int k = threadIdx.x;
  const int t = targets[b];
  const int pr = all_prx[t];
  if (k == 0) prxArr[b] = pr;
  A2[b * D_DIM + k] = features[b * D_DIM + k];
  A2[(B_SZ + b) * D_DIM + k] = mem[(size_t)pr * D_DIM + k];
}

// ---------------- kernel 1: split-fp16 3-pass MFMA GEMM ----------------
// OUT[r][p] = sum_k A'[r][k]*mem[p][k]  (NT, both row-major K-contiguous)
// f32 = hi(fp16) + lo(fp16); C = Ah*Bh + Ah*Bl + Al*Bh  (lo*lo dropped, ~2^-21)
__global__ __launch_bounds__(256) void gemm_mfma(const float* __restrict__ A,
                                                 const float* __restrict__ Bm,
                                                 float* __restrict__ Co) {
  __shared__ _Float16 Ah[128][32], Al[128][32], Bh[128][32], Bl[128][32];
  const int tid = threadIdx.x;
  const int lane = tid & 63;
  const int wid = tid >> 6;
  const int wr = wid >> 1, wc = wid & 1;     // 2x2 waves, 64x64 each
  // XCD swizzle: 1024 blocks, 8 XCDs -> the 4 row-blocks of one col-stripe
  // are consecutive within an XCD (B-panel L2 reuse).
  const int orig = (blockIdx.x & 7) * 128 + (blockIdx.x >> 3);
  const int rowBase = (orig & 3) << 7;       // 4 row-blocks over M=512
  const int colBase = (orig >> 2) << 7;      // 256 col-blocks over N=32768

  const int trow = tid >> 3;                 // 0..31
  const int tseg = tid & 7;                  // 0..7, 4 floats each

  floatx4 acc[4][4];
#pragma unroll
  for (int i = 0; i < 4; ++i)
#pragma unroll
    for (int j = 0; j < 4; ++j) {
      acc[i][j][0] = 0.f; acc[i][j][1] = 0.f; acc[i][j][2] = 0.f; acc[i][j][3] = 0.f;
    }

  const int fr = lane & 15;
  const int kg = (lane >> 4) << 3;           // k-group offset (0,8,16,24)

  for (int step = 0; step < 8; ++step) {
    const int k0 = step << 5;
    float4 sa[4], sb[4];
#pragma unroll
    for (int p = 0; p < 4; ++p) {
      const int r = trow + (p << 5);
      sa[p] = *(const float4*)(A  + (size_t)(rowBase + r) * D_DIM + k0 + tseg * 4);
      sb[p] = *(const float4*)(Bm + (size_t)(colBase + r) * D_DIM + k0 + tseg * 4);
    }
    __syncthreads();     // previous iteration's LDS reads complete
#pragma unroll
    for (int p = 0; p < 4; ++p) {
      const int r = trow + (p << 5);
      float4 v = sa[p];
      half4v h, l;
      h[0] = (_Float16)v.x; l[0] = (_Float16)(v.x - (float)h[0]);
      h[1] = (_Float16)v.y; l[1] = (_Float16)(v.y - (float)h[1]);
      h[2] = (_Float16)v.z; l[2] = (_Float16)(v.z - (float)h[2]);
      h[3] = (_Float16)v.w; l[3] = (_Float16)(v.w - (float)h[3]);
      *(half4v*)&Ah[r][tseg * 4] = h;
      *(half4v*)&Al[r][tseg * 4] = l;
      v = sb[p];
      h[0] = (_Float16)v.x; l[0] = (_Float16)(v.x - (float)h[0]);
      h[1] = (_Float16)v.y; l[1] = (_Float16)(v.y - (float)h[1]);
      h[2] = (_Float16)v.z; l[2] = (_Float16)(v.z - (float)h[2]);
      h[3] = (_Float16)v.w; l[3] = (_Float16)(v.w - (float)h[3]);
      *(half4v*)&Bh[r][tseg * 4] = h;
      *(half4v*)&Bl[r][tseg * 4] = l;
    }
    __syncthreads();     // staged tile visible
    half8 ah[4], al[4], bh[4], bl[4];
#pragma unroll
    for (int f = 0; f < 4; ++f) {
      ah[f] = *(const half8*)&Ah[wr * 64 + f * 16 + fr][kg];
      al[f] = *(const half8*)&Al[wr * 64 + f * 16 + fr][kg];
      bh[f] = *(const half8*)&Bh[wc * 64 + f * 16 + fr][kg];
      bl[f] = *(const half8*)&Bl[wc * 64 + f * 16 + fr][kg];
    }
#pragma unroll
    for (int fm = 0; fm < 4; ++fm)
#pragma unroll
      for (int fn = 0; fn < 4; ++fn) {
        acc[fm][fn] = __builtin_amdgcn_mfma_f32_16x16x32_f16(ah[fm], bh[fn], acc[fm][fn], 0, 0, 0);
        acc[fm][fn] = __builtin_amdgcn_mfma_f32_16x16x32_f16(ah[fm], bl[fn], acc[fm][fn], 0, 0, 0);
        acc[fm][fn] = __builtin_amdgcn_mfma_f32_16x16x32_f16(al[fm], bh[fn], acc[fm][fn], 0, 0, 0);
      }
  }
  // epilogue: C/D layout col = lane&15, row = (lane>>4)*4 + reg
  const int rsub = (lane >> 4) << 2;
#pragma unroll
  for (int fm = 0; fm < 4; ++fm)
#pragma unroll
    for (int fn = 0; fn < 4; ++fn) {
      const int r0 = rowBase + wr * 64 + fm * 16 + rsub;
      const int c0 = colBase + wc * 64 + fn * 16 + fr;
#pragma unroll
      for (int r = 0; r < 4; ++r)
        Co[(size_t)(r0 + r) * P_CNT + c0] = acc[fm][fn][r];
    }
}

// ---------------- kernel 2: per-sample losses (one 1024-thread block per sample) ----------------
__global__ __launch_bounds__(NTHR) void persample(const float* __restrict__ OUT,
                                                  const int* __restrict__ cams,
                                                  const int* __restrict__ prxArr,
                                                  float* __restrict__ intraArr,
                                                  float* __restrict__ crossArr,
                                                  float* __restrict__ onlArr) {
  __shared__ float row[P_CNT];      // 128 KiB: score row, then sims row
  __shared__ int   histW[NW * 16];
  __shared__ int   histT[16];
  __shared__ float bufV[64];
  __shared__ int   bufI[32];
  __shared__ int   cntS[4];
  __shared__ float redW[NW];
  __shared__ float sv[64];
  __shared__ int   si[64];
  __shared__ float cvW[NW * 8];
  __shared__ int   ciW[NW * 8];
  __shared__ float mw[NW], sw[NW];
  __shared__ float bcast[2];

  const int b = blockIdx.x;
  const int tid = threadIdx.x;
  const int lane = tid & 63, wid = tid >> 6;
  const float* Srow = OUT + (size_t)b * P_CNT;
  const float* Mrow = OUT + (size_t)(B_SZ + b) * P_CNT;
  const int pr = prxArr[b];
  const int cam = cams[b];
  float4* row4 = (float4*)row;
  const int camHi = cam >> 2, camLo = cam & 3;

  // ---- stage score row into LDS; fold in row-max and intra online-LSE ----
  float pmax = NEG_BIG;
  float im = NEG_BIG, is = 0.f;
  for (int i = tid; i < P_CNT / 4; i += NTHR) {
    float4 q = ((const float4*)Srow)[i];
    row4[i] = q;
    pmax = fmaxf(fmaxf(fmaxf(q.x, q.y), fmaxf(q.z, q.w)), pmax);
    if ((i & 1) == camHi) {
      float v = (camLo == 0) ? q.x : (camLo == 1) ? q.y : (camLo == 2) ? q.z : q.w;
      if (v <= im) is += expf((v - im) * INVT);
      else { is = is * expf((im - v) * INVT) + 1.f; im = v; }
    }
  }
  __syncthreads();
  const float M = blockMax(pmax, tid, redW);

#pragma unroll
  for (int off = 1; off < 64; off <<= 1) {
    float m2 = __shfl_xor(im, off);
    float s2 = __shfl_xor(is, off);
    float Mx = fmaxf(im, m2);
    is = is * expf((im - Mx) * INVT) + s2 * expf((m2 - Mx) * INVT);
    im = Mx;
  }
  if (lane == 0) { mw[wid] = im; sw[wid] = is; }
  __syncthreads();
  if (tid == 0) {
    float m0 = mw[0], s0 = sw[0];
    for (int w = 1; w < NW; ++w) {
      float Mx = fmaxf(m0, mw[w]);
      s0 = s0 * expf((m0 - Mx) * INVT) + sw[w] * expf((mw[w] - Mx) * INVT);
      m0 = Mx;
    }
    intraArr[b] = -((row[pr] - m0) * INVT - logf(s0));
  }
  __syncthreads();

  // ---- cross: pos = [pr&~7 .. +7]; exact 50th of the rest via radix select ----
  const int posBase = pr & ~7;
  if (tid < 8) { sv[tid] = row[posBase + tid]; row[posBase + tid] = NEG_BIG; }
  __syncthreads();
  const float vk = radixSelectK(row, 50, tid, histW, histT, bufV, cntS, bcast);
  {
    float se = 0.f, cg = 0.f;
    for (int i = tid; i < P_CNT / 4; i += NTHR) {
      float4 q = row4[i];
      if (q.x > vk) { se += expf((q.x - M) * INVT); cg += 1.f; }
      if (q.y > vk) { se += expf((q.y - M) * INVT); cg += 1.f; }
      if (q.z > vk) { se += expf((q.z - M) * INVT); cg += 1.f; }
      if (q.w > vk) { se += expf((q.w - M) * INVT); cg += 1.f; }
    }
    se = blockSum(se, tid, redW);
    cg = blockSum(cg, tid, redW);
    if (tid == 0) {
      float stot = se + (50.f - cg) * expf((vk - M) * INVT);
      for (int p = 0; p < 8; ++p) stot += expf((sv[p] - M) * INVT);
      float lse = logf(stot);
      float acc = 0.f;
      for (int p = 0; p < 8; ++p) acc += (sv[p] - M) * INVT - lse;
      crossArr[b] = -acc * 0.125f;
    }
  }
  if (tid < 8) row[posBase + tid] = sv[tid];
  __syncthreads();

  // ---- online: row := sims = 0.15*score + 0.85*memsim ----
  for (int i = tid; i < P_CNT / 4; i += NTHR) {
    float4 v = row4[i];
    float4 m2 = ((const float4*)Mrow)[i];
    v.x = 0.15f * v.x + 0.85f * m2.x;
    v.y = 0.15f * v.y + 0.85f * m2.y;
    v.z = 0.15f * v.z + 0.85f * m2.z;
    v.w = 0.15f * v.w + 0.85f * m2.w;
    row4[i] = v;
  }
  __syncthreads();

  // per-camera argmax over sims: thread tid sees p%8 == tid%8 (conflict-free)
  {
    float bm = NEG_BIG; int bi = 0x7fffffff;
    for (int p = tid; p < P_CNT; p += NTHR) {
      float v = row[p];
      if (v > bm) { bm = v; bi = p; }
    }
#pragma unroll
    for (int off = 8; off <= 32; off <<= 1) {
      float v2 = __shfl_xor(bm, off);
      int   i2 = __shfl_xor(bi, off);
      if (v2 > bm || (v2 == bm && i2 < bi)) { bm = v2; bi = i2; }
    }
    if (lane < 8) { cvW[wid * 8 + lane] = bm; ciW[wid * 8 + lane] = bi; }
    __syncthreads();
    if (tid < 8) {
      float v = cvW[tid]; int ix = ciW[tid];
      for (int w = 1; w < NW; ++w) {
        float v2 = cvW[w * 8 + tid]; int i2 = ciW[w * 8 + tid];
        if (v2 > v || (v2 == v && i2 < ix)) { v = v2; ix = i2; }
      }
      cvW[tid] = v; ciW[tid] = ix;
    }
    __syncthreads();
    if (tid == 0) {
      unsigned used = 0;
      for (int k = 0; k < 3; ++k) {
        float best = NEG_BIG; int bc = 0;
        for (int c = 0; c < 8; ++c)
          if (!((used >> c) & 1u) && cvW[c] > best) { best = cvW[c]; bc = c; }
        used |= 1u << bc;
        si[k] = ciW[bc];
        row[ciW[bc]] = NEG_BIG;
      }
    }
    __syncthreads();
  }

  // exact 50th of remaining sims; collect indices (greater + smallest-index equals)
  const float vk2 = radixSelectK(row, 50, tid, histW, histT, bufV, cntS, bcast);
  if (tid == 0) { cntS[1] = 0; cntS[2] = 0; }
  __syncthreads();
  for (int i = tid; i < P_CNT; i += NTHR) {
    float v = row[i];
    if (v > vk2) {
      int p = atomicAdd(&cntS[1], 1);
      if (p < 50) si[3 + p] = i;
    } else if (v == vk2) {
      int p = atomicAdd(&cntS[2], 1);
      if (p < 32) bufI[p] = i;
    }
  }
  __syncthreads();
  {
    const int cg = cntS[1];
    const int fill = 50 - cg;
    if (tid < 64) {
      int ne = min(cntS[2], 32);
      int il = (tid < ne) ? bufI[tid] : 0x7fffffff;
      for (int it = 0; it < fill; ++it) {
        int wi = il;
#pragma unroll
        for (int off = 1; off < 64; off <<= 1) wi = min(wi, __shfl_xor(wi, off));
        if (tid == 0) si[3 + cg + it] = wi;
        if (il == wi) il = 0x7fffffff;
      }
    }
  }
  __syncthreads();
  if (tid < 53) sv[tid] = Srow[si[tid]];
  __syncthreads();
  if (tid < 64) {
    float v = (tid < 53) ? sv[tid] : NEG_BIG;
    float mm = v;
#pragma unroll
    for (int off = 1; off < 64; off <<= 1) mm = fmaxf(mm, __shfl_xor(mm, off));
    float e = (tid < 53) ? expf((v - mm) * INVT) : 0.f;
    float ss = e;
#pragma unroll
    for (int off = 1; off < 64; off <<= 1) ss += __shfl_xor(ss, off);
    float lse = logf(ss);
    float c = (tid < 3) ? ((v - mm) * INVT - lse) : 0.f;
#pragma unroll
    for (int off = 1; off < 64; off <<= 1) c += __shfl_xor(c, off);
    if (tid == 0) onlArr[b] = -c * (1.0f / 3.0f);
  }
}

// ---------------- kernel 3: per-camera means -> scalar ----------------
__global__ void finalize(const int* __restrict__ cams,
                         const float* __restrict__ ia,
                         const float* __restrict__ ca,
                         const float* __restrict__ oa,
                         float* __restrict__ out) {
  if (blockIdx.x == 0 && threadIdx.x == 0) {
    float s[8] = {}; float n[8] = {};
    for (int b = 0; b < B_SZ; ++b) {
      int c = cams[b];
      s[c] += ia[b] + ca[b] + oa[b];
      n[c] += 1.f;
    }
    float tot = 0.f;
    for (int c = 0; c < 8; ++c)
      if (n[c] > 0.f) tot += s[c] / n[c];
    out[0] = tot;
  }
}

extern "C" void kernel_launch(void* const* d_in, const int* in_sizes, int n_in,
                              void* d_out, int out_size, void* d_ws, size_t ws_size,
                              hipStream_t stream) {
  const float* features = (const float*)d_in[0];
  const int*   targets  = (const int*)d_in[1];
  const int*   cams     = (const int*)d_in[2];
  const float* mem      = (const float*)d_in[4];
  const int*   all_prx  = (const int*)d_in[6];

  float* ws = (float*)d_ws;
  float* A2  = ws;                               // 512*256
  float* OUT = ws + 512 * D_DIM;                 // 512*32768
  float* tail = OUT + (size_t)512 * P_CNT;
  int*   prxArr  = (int*)tail;                   // 256
  float* intraArr = (float*)(prxArr + B_SZ);     // 256
  float* crossArr = intraArr + B_SZ;             // 256
  float* onlArr   = crossArr + B_SZ;             // 256

  prep_kernel<<<B_SZ, D_DIM, 0, stream>>>(features, targets, all_prx, mem, A2, prxArr);
  gemm_mfma<<<1024, 256, 0, stream>>>(A2, mem, OUT);
  persample<<<B_SZ, NTHR, 0, stream>>>(OUT, cams, prxArr, intraArr, crossArr, onlArr);
  finalize<<<1, 64, 0, stream>>>(cams, intraArr, crossArr, onlArr, (float*)d_out);
}

// Round 6
// 178.358 us; speedup vs baseline: 2.9076x; 1.0101x over previous
//
#include <hip/hip_runtime.h>

#define P_CNT 32768
#define D_DIM 256
#define B_SZ  256
#define NTHR  1024
#define NW    16
#define INVT  20.0f          // 1/TEMP
#define NEG_BIG -3.0e38f

typedef _Float16 half8  __attribute__((ext_vector_type(8)));
typedef _Float16 half4v __attribute__((ext_vector_type(4)));
typedef float    floatx4 __attribute__((ext_vector_type(4)));

// ---------------- block reduction helpers (1024 threads, wave64) ----------------
__device__ __forceinline__ float blockMax(float v, int tid, float* redW) {
#pragma unroll
  for (int off = 1; off < 64; off <<= 1) v = fmaxf(v, __shfl_xor(v, off));
  if ((tid & 63) == 0) redW[tid >> 6] = v;
  __syncthreads();
  float r = redW[0];
#pragma unroll
  for (int w = 1; w < NW; ++w) r = fmaxf(r, redW[w]);
  __syncthreads();
  return r;
}

__device__ __forceinline__ float blockSum(float v, int tid, float* redW) {
#pragma unroll
  for (int off = 1; off < 64; off <<= 1) v += __shfl_xor(v, off);
  if ((tid & 63) == 0) redW[tid >> 6] = v;
  __syncthreads();
  float r = 0.f;
#pragma unroll
  for (int w = 0; w < NW; ++w) r += redW[w];
  __syncthreads();
  return r;
}

// ---------------- exact k-th largest via 4-bit radix select over REGISTER data ----
// getv(j) returns this thread's j-th value (j in [0,32), fully unrolled callers).
template <typename GetV>
__device__ __forceinline__ float radixSelectReg(GetV getv, int k, int tid,
                                                int* histW /*NW*16*/, int* histT /*16*/,
                                                float* bufV /*64*/, int* cntS,
                                                float* bcast) {
  const int lane = tid & 63, wid = tid >> 6;
  unsigned prefix = 0;
  int krem = k;
  int shift = 28;
  for (;;) {
    unsigned long long accLo = 0ull, accHi = 0ull;
    const int sh4 = shift + 4;
#pragma unroll
    for (int j = 0; j < 32; ++j) {
      float v = getv(j);
      unsigned bu = __float_as_uint(v);
      unsigned key = bu ^ ((unsigned)(((int)bu) >> 31) | 0x80000000u);
      bool ok = (sh4 >= 32) || ((key >> sh4) == prefix);
      int bin = (key >> shift) & 15;
      unsigned long long one = ok ? 1ull : 0ull;
      if (bin < 8) accLo += one << (bin << 3);
      else         accHi += one << ((bin - 8) << 3);
    }
    int cnt[16];
#pragma unroll
    for (int j = 0; j < 8; ++j) cnt[j] = (int)((accLo >> (j * 8)) & 0xffull);
#pragma unroll
    for (int j = 0; j < 8; ++j) cnt[8 + j] = (int)((accHi >> (j * 8)) & 0xffull);
#pragma unroll
    for (int j = 0; j < 16; ++j) {
      int v = cnt[j];
#pragma unroll
      for (int off = 1; off < 64; off <<= 1) v += __shfl_xor(v, off);
      cnt[j] = v;
    }
    if (lane == 0) {
#pragma unroll
      for (int j = 0; j < 16; ++j) histW[wid * 16 + j] = cnt[j];
    }
    __syncthreads();
    if (tid < 16) {
      int sacc = 0;
#pragma unroll
      for (int w = 0; w < NW; ++w) sacc += histW[w * 16 + tid];
      histT[tid] = sacc;
    }
    __syncthreads();
    int t = -1, above = 0, cntT = 0;
#pragma unroll
    for (int j = 15; j >= 0; --j) {
      int tj = histT[j];
      if (t < 0) {
        if (above + tj >= krem) { t = j; cntT = tj; }
        else above += tj;
      }
    }
    krem -= above;
    prefix = (prefix << 4) | (unsigned)t;
    if (cntT <= 64 || shift == 0) break;
    shift -= 4;
  }
  // collect candidates with exact key-prefix match
  if (tid == 0) cntS[0] = 0;
  __syncthreads();
#pragma unroll
  for (int j = 0; j < 32; ++j) {
    float v = getv(j);
    unsigned bu = __float_as_uint(v);
    unsigned key = bu ^ ((unsigned)(((int)bu) >> 31) | 0x80000000u);
    if ((key >> shift) == prefix) {
      int p = atomicAdd(cntS, 1);
      if (p < 64) bufV[p] = v;
    }
  }
  __syncthreads();
  if (tid < 64) {
    int n = min(cntS[0], 64);
    float vl = (tid < n) ? bufV[tid] : NEG_BIG;
    float vkv = NEG_BIG;
    for (int it = 0; it < krem; ++it) {
      float wv = vl;
#pragma unroll
      for (int off = 1; off < 64; off <<= 1) wv = fmaxf(wv, __shfl_xor(wv, off));
      if (it == krem - 1) vkv = wv;
      unsigned long long m = __ballot(vl == wv);
      int fl = (int)__ffsll(m) - 1;
      if (tid == fl) vl = NEG_BIG;
    }
    if (tid == 0) bcast[0] = vkv;
  }
  __syncthreads();
  float r = bcast[0];
  __syncthreads();
  return r;
}

// ---------------- kernel 0: gather prx, build A' = [features; mem[prx]] ----------------
__global__ void prep_kernel(const float* __restrict__ features,
                            const int* __restrict__ targets,
                            const int* __restrict__ all_prx,
                            const float* __restrict__ mem,
                            float* __restrict__ A2,
                            int* __restrict__ prxArr) {
  const int b = blockIdx.x;
  const int k = threadIdx.x;
  const int t = targets[b];
  const int pr = all_prx[t];
  if (k == 0) prxArr[b] = pr;
  A2[b * D_DIM + k] = features[b * D_DIM + k];
  A2[(B_SZ + b) * D_DIM + k] = mem[(size_t)pr * D_DIM + k];
}

// ---------------- kernel 1: split-fp16 3-pass MFMA GEMM ----------------
__global__ __launch_bounds__(256) void gemm_mfma(const float* __restrict__ A,
                                                 const float* __restrict__ Bm,
                                                 float* __restrict__ Co) {
  __shared__ _Float16 Ah[128][32], Al[128][32], Bh[128][32], Bl[128][32];
  const int tid = threadIdx.x;
  const int lane = tid & 63;
  const int wid = tid >> 6;
  const int wr = wid >> 1, wc = wid & 1;     // 2x2 waves, 64x64 each
  const int orig = (blockIdx.x & 7) * 128 + (blockIdx.x >> 3);
  const int rowBase = (orig & 3) << 7;
  const int colBase = (orig >> 2) << 7;

  const int trow = tid >> 3;
  const int tseg = tid & 7;

  floatx4 acc[4][4];
#pragma unroll
  for (int i = 0; i < 4; ++i)
#pragma unroll
    for (int j = 0; j < 4; ++j) {
      acc[i][j][0] = 0.f; acc[i][j][1] = 0.f; acc[i][j][2] = 0.f; acc[i][j][3] = 0.f;
    }

  const int fr = lane & 15;
  const int kg = (lane >> 4) << 3;

  for (int step = 0; step < 8; ++step) {
    const int k0 = step << 5;
    float4 sa[4], sb[4];
#pragma unroll
    for (int p = 0; p < 4; ++p) {
      const int r = trow + (p << 5);
      sa[p] = *(const float4*)(A  + (size_t)(rowBase + r) * D_DIM + k0 + tseg * 4);
      sb[p] = *(const float4*)(Bm + (size_t)(colBase + r) * D_DIM + k0 + tseg * 4);
    }
    __syncthreads();
#pragma unroll
    for (int p = 0; p < 4; ++p) {
      const int r = trow + (p << 5);
      float4 v = sa[p];
      half4v h, l;
      h[0] = (_Float16)v.x; l[0] = (_Float16)(v.x - (float)h[0]);
      h[1] = (_Float16)v.y; l[1] = (_Float16)(v.y - (float)h[1]);
      h[2] = (_Float16)v.z; l[2] = (_Float16)(v.z - (float)h[2]);
      h[3] = (_Float16)v.w; l[3] = (_Float16)(v.w - (float)h[3]);
      *(half4v*)&Ah[r][tseg * 4] = h;
      *(half4v*)&Al[r][tseg * 4] = l;
      v = sb[p];
      h[0] = (_Float16)v.x; l[0] = (_Float16)(v.x - (float)h[0]);
      h[1] = (_Float16)v.y; l[1] = (_Float16)(v.y - (float)h[1]);
      h[2] = (_Float16)v.z; l[2] = (_Float16)(v.z - (float)h[2]);
      h[3] = (_Float16)v.w; l[3] = (_Float16)(v.w - (float)h[3]);
      *(half4v*)&Bh[r][tseg * 4] = h;
      *(half4v*)&Bl[r][tseg * 4] = l;
    }
    __syncthreads();
    half8 ah[4], al[4], bh[4], bl[4];
#pragma unroll
    for (int f = 0; f < 4; ++f) {
      ah[f] = *(const half8*)&Ah[wr * 64 + f * 16 + fr][kg];
      al[f] = *(const half8*)&Al[wr * 64 + f * 16 + fr][kg];
      bh[f] = *(const half8*)&Bh[wc * 64 + f * 16 + fr][kg];
      bl[f] = *(const half8*)&Bl[wc * 64 + f * 16 + fr][kg];
    }
#pragma unroll
    for (int fm = 0; fm < 4; ++fm)
#pragma unroll
      for (int fn = 0; fn < 4; ++fn) {
        acc[fm][fn] = __builtin_amdgcn_mfma_f32_16x16x32_f16(ah[fm], bh[fn], acc[fm][fn], 0, 0, 0);
        acc[fm][fn] = __builtin_amdgcn_mfma_f32_16x16x32_f16(ah[fm], bl[fn], acc[fm][fn], 0, 0, 0);
        acc[fm][fn] = __builtin_amdgcn_mfma_f32_16x16x32_f16(al[fm], bh[fn], acc[fm][fn], 0, 0, 0);
      }
  }
  const int rsub = (lane >> 4) << 2;
#pragma unroll
  for (int fm = 0; fm < 4; ++fm)
#pragma unroll
    for (int fn = 0; fn < 4; ++fn) {
      const int r0 = rowBase + wr * 64 + fm * 16 + rsub;
      const int c0 = colBase + wc * 64 + fn * 16 + fr;
#pragma unroll
      for (int r = 0; r < 4; ++r)
        Co[(size_t)(r0 + r) * P_CNT + c0] = acc[fm][fn][r];
    }
}

// ---------------- kernel 2: per-sample losses — register-resident row ----------------
// Thread owns elements p(j) = 4*tid + 4096*(j>>2) + (j&3), j in [0,32).
__global__ __launch_bounds__(NTHR) void persample(const float* __restrict__ OUT,
                                                  const int* __restrict__ cams,
                                                  const int* __restrict__ prxArr,
                                                  float* __restrict__ intraArr,
                                                  float* __restrict__ crossArr,
                                                  float* __restrict__ onlArr) {
  __shared__ int   histW[NW * 16];
  __shared__ int   histT[16];
  __shared__ float bufV[64];
  __shared__ int   bufI[32];
  __shared__ int   cntS[4];
  __shared__ float redW[NW];
  __shared__ float sv[64];
  __shared__ int   si[64];
  __shared__ float cvW[NW * 8];
  __shared__ int   ciW[NW * 8];
  __shared__ float mw[NW], sw[NW];
  __shared__ float bcast[2];

  const int b = blockIdx.x;
  const int tid = threadIdx.x;
  const int lane = tid & 63, wid = tid >> 6;
  const float* Srow = OUT + (size_t)b * P_CNT;
  const float* Mrow = OUT + (size_t)(B_SZ + b) * P_CNT;
  const int pr = prxArr[b];
  const int cam = cams[b];
  const int base4 = tid << 2;

  // ---- load score row into registers (coalesced float4) ----
  float s[32];
#pragma unroll
  for (int q = 0; q < 8; ++q) {
    float4 f = ((const float4*)Srow)[tid + (q << 10)];
    s[4 * q + 0] = f.x; s[4 * q + 1] = f.y; s[4 * q + 2] = f.z; s[4 * q + 3] = f.w;
  }
  float pmax = NEG_BIG;
#pragma unroll
  for (int j = 0; j < 32; ++j) pmax = fmaxf(pmax, s[j]);
  const float M = blockMax(pmax, tid, redW);

  // ---- intra: online LSE over {p : p%8==cam}; this thread holds them iff parity matches ----
  {
    const bool mine = ((tid & 1) == (cam >> 2));
    const int cc = cam & 3;
    float im = NEG_BIG, is = 0.f;
    if (mine) {
#pragma unroll
      for (int q = 0; q < 8; ++q) {
        float v = (cc == 0) ? s[4 * q] : (cc == 1) ? s[4 * q + 1]
                : (cc == 2) ? s[4 * q + 2] : s[4 * q + 3];
        if (v <= im) is += expf((v - im) * INVT);
        else { is = is * expf((im - v) * INVT) + 1.f; im = v; }
      }
    }
#pragma unroll
    for (int off = 1; off < 64; off <<= 1) {
      float m2 = __shfl_xor(im, off);
      float s2 = __shfl_xor(is, off);
      float Mx = fmaxf(im, m2);
      is = is * expf((im - Mx) * INVT) + s2 * expf((m2 - Mx) * INVT);
      im = Mx;
    }
    if (lane == 0) { mw[wid] = im; sw[wid] = is; }
  }
  __syncthreads();
  if (tid == 0) {
    float m0 = mw[0], s0 = sw[0];
    for (int w = 1; w < NW; ++w) {
      float Mx = fmaxf(m0, mw[w]);
      s0 = s0 * expf((m0 - Mx) * INVT) + sw[w] * expf((mw[w] - Mx) * INVT);
      m0 = Mx;
    }
    intraArr[b] = -((Srow[pr] - m0) * INVT - logf(s0));
  }

  // ---- cross: exclude pos=[posBase..+8); exact 50th of rest; LSE ----
  const int posBase = pr & ~7;
  if (tid < 8) sv[tid] = Srow[posBase + tid];
  __syncthreads();
  auto crossVal = [&](int j) -> float {
    int p = base4 + ((j >> 2) << 12) + (j & 3);
    return ((unsigned)(p - posBase) < 8u) ? NEG_BIG : s[j];
  };
  const float vk = radixSelectReg(crossVal, 50, tid, histW, histT, bufV, cntS, bcast);
  {
    float se = 0.f, cg = 0.f;
#pragma unroll
    for (int j = 0; j < 32; ++j) {
      float v = crossVal(j);
      if (v > vk) { se += expf((v - M) * INVT); cg += 1.f; }
    }
    se = blockSum(se, tid, redW);
    cg = blockSum(cg, tid, redW);
    if (tid == 0) {
      float stot = se + (50.f - cg) * expf((vk - M) * INVT);
      for (int p = 0; p < 8; ++p) stot += expf((sv[p] - M) * INVT);
      float lse = logf(stot);
      float acc = 0.f;
      for (int p = 0; p < 8; ++p) acc += (sv[p] - M) * INVT - lse;
      crossArr[b] = -acc * 0.125f;
    }
  }

  // ---- sims in place: s := 0.15*score + 0.85*memsim ----
#pragma unroll
  for (int q = 0; q < 8; ++q) {
    float4 m2 = ((const float4*)Mrow)[tid + (q << 10)];
    s[4 * q + 0] = 0.15f * s[4 * q + 0] + 0.85f * m2.x;
    s[4 * q + 1] = 0.15f * s[4 * q + 1] + 0.85f * m2.y;
    s[4 * q + 2] = 0.15f * s[4 * q + 2] + 0.85f * m2.z;
    s[4 * q + 3] = 0.15f * s[4 * q + 3] + 0.85f * m2.w;
  }

  // ---- per-camera argmax: thread parity covers 4 of 8 cameras ----
  {
    float cm[4] = {NEG_BIG, NEG_BIG, NEG_BIG, NEG_BIG};
    int cix[4] = {0x7fffffff, 0x7fffffff, 0x7fffffff, 0x7fffffff};
#pragma unroll
    for (int q = 0; q < 8; ++q) {
#pragma unroll
      for (int c = 0; c < 4; ++c) {
        float v = s[4 * q + c];
        int p = base4 + (q << 12) + c;
        if (v > cm[c]) { cm[c] = v; cix[c] = p; }
      }
    }
    const bool odd = (tid & 1);
    float v8[8]; int i8[8];
#pragma unroll
    for (int c = 0; c < 4; ++c) {
      float ov = __shfl_xor(cm[c], 1); int oi = __shfl_xor(cix[c], 1);
      v8[c]     = odd ? ov : cm[c];   i8[c]     = odd ? oi : cix[c];
      v8[c + 4] = odd ? cm[c] : ov;   i8[c + 4] = odd ? cix[c] : oi;
    }
#pragma unroll
    for (int off = 2; off <= 32; off <<= 1) {
#pragma unroll
      for (int c = 0; c < 8; ++c) {
        float vv = __shfl_xor(v8[c], off);
        int   ii = __shfl_xor(i8[c], off);
        if (vv > v8[c] || (vv == v8[c] && ii < i8[c])) { v8[c] = vv; i8[c] = ii; }
      }
    }
    if (lane < 8) {
#pragma unroll
      for (int c = 0; c < 8; ++c)
        if (lane == c) { cvW[wid * 8 + c] = v8[c]; ciW[wid * 8 + c] = i8[c]; }
    }
    __syncthreads();
    if (tid < 8) {
      float v = cvW[tid]; int ix = ciW[tid];
      for (int w = 1; w < NW; ++w) {
        float v2 = cvW[w * 8 + tid]; int i2 = ciW[w * 8 + tid];
        if (v2 > v || (v2 == v && i2 < ix)) { v = v2; ix = i2; }
      }
      cvW[tid] = v; ciW[tid] = ix;
    }
    __syncthreads();
    if (tid == 0) {
      unsigned used = 0;
      for (int k = 0; k < 3; ++k) {
        float best = NEG_BIG; int bc = 0;
        for (int c = 0; c < 8; ++c)
          if (!((used >> c) & 1u) && cvW[c] > best) { best = cvW[c]; bc = c; }
        used |= 1u << bc;
        si[k] = ciW[bc];
      }
    }
    __syncthreads();
  }
  const int c0 = si[0], c1 = si[1], c2 = si[2];
  __syncthreads();

  // ---- online: exclude chosen; exact 50th of rest; collect indices ----
  auto simsVal = [&](int j) -> float {
    int p = base4 + ((j >> 2) << 12) + (j & 3);
    return (p == c0 || p == c1 || p == c2) ? NEG_BIG : s[j];
  };
  const float vk2 = radixSelectReg(simsVal, 50, tid, histW, histT, bufV, cntS, bcast);
  if (tid == 0) { cntS[1] = 0; cntS[2] = 0; }
  __syncthreads();
#pragma unroll
  for (int j = 0; j < 32; ++j) {
    float v = simsVal(j);
    int p = base4 + ((j >> 2) << 12) + (j & 3);
    if (v > vk2) {
      int t = atomicAdd(&cntS[1], 1);
      if (t < 50) si[3 + t] = p;
    } else if (v == vk2) {
      int t = atomicAdd(&cntS[2], 1);
      if (t < 32) bufI[t] = p;
    }
  }
  __syncthreads();
  {
    const int cg = cntS[1];
    const int fill = 50 - cg;
    if (tid < 64) {
      int ne = min(cntS[2], 32);
      int il = (tid < ne) ? bufI[tid] : 0x7fffffff;
      for (int it = 0; it < fill; ++it) {
        int wi = il;
#pragma unroll
        for (int off = 1; off < 64; off <<= 1) wi = min(wi, __shfl_xor(wi, off));
        if (tid == 0) si[3 + cg + it] = wi;
        if (il == wi) il = 0x7fffffff;
      }
    }
  }
  __syncthreads();
  if (tid < 53) sv[tid] = Srow[si[tid]];   // gather scores at selected indices (L2-hot)
  __syncthreads();
  if (tid < 64) {
    float v = (tid < 53) ? sv[tid] : NEG_BIG;
    float mm = v;
#pragma unroll
    for (int off = 1; off < 64; off <<= 1) mm = fmaxf(mm, __shfl_xor(mm, off));
    float e = (tid < 53) ? expf((v - mm) * INVT) : 0.f;
    float ss = e;
#pragma unroll
    for (int off = 1; off < 64; off <<= 1) ss += __shfl_xor(ss, off);
    float lse = logf(ss);
    float c = (tid < 3) ? ((v - mm) * INVT - lse) : 0.f;
#pragma unroll
    for (int off = 1; off < 64; off <<= 1) c += __shfl_xor(c, off);
    if (tid == 0) onlArr[b] = -c * (1.0f / 3.0f);
  }
}

// ---------------- kernel 3: per-camera means -> scalar ----------------
__global__ void finalize(const int* __restrict__ cams,
                         const float* __restrict__ ia,
                         const float* __restrict__ ca,
                         const float* __restrict__ oa,
                         float* __restrict__ out) {
  if (blockIdx.x == 0 && threadIdx.x == 0) {
    float s[8] = {}; float n[8] = {};
    for (int b = 0; b < B_SZ; ++b) {
      int c = cams[b];
      s[c] += ia[b] + ca[b] + oa[b];
      n[c] += 1.f;
    }
    float tot = 0.f;
    for (int c = 0; c < 8; ++c)
      if (n[c] > 0.f) tot += s[c] / n[c];
    out[0] = tot;
  }
}

extern "C" void kernel_launch(void* const* d_in, const int* in_sizes, int n_in,
                              void* d_out, int out_size, void* d_ws, size_t ws_size,
                              hipStream_t stream) {
  const float* features = (const float*)d_in[0];
  const int*   targets  = (const int*)d_in[1];
  const int*   cams     = (const int*)d_in[2];
  const float* mem      = (const float*)d_in[4];
  const int*   all_prx  = (const int*)d_in[6];

  float* ws = (float*)d_ws;
  float* A2  = ws;                               // 512*256
  float* OUT = ws + 512 * D_DIM;                 // 512*32768
  float* tail = OUT + (size_t)512 * P_CNT;
  int*   prxArr  = (int*)tail;                   // 256
  float* intraArr = (float*)(prxArr + B_SZ);     // 256
  float* crossArr = intraArr + B_SZ;             // 256
  float* onlArr   = crossArr + B_SZ;             // 256

  prep_kernel<<<B_SZ, D_DIM, 0, stream>>>(features, targets, all_prx, mem, A2, prxArr);
  gemm_mfma<<<1024, 256, 0, stream>>>(A2, mem, OUT);
  persample<<<B_SZ, NTHR, 0, stream>>>(OUT, cams, prxArr, intraArr, crossArr, onlArr);
  finalize<<<1, 64, 0, stream>>>(cams, intraArr, crossArr, onlArr, (float*)d_out);
}

// Round 7
// 143.706 us; speedup vs baseline: 3.6087x; 1.2411x over previous
//
#include <hip/hip_runtime.h>

#define P_CNT 32768
#define D_DIM 256
#define B_SZ  256
#define NTHR  1024
#define NW    16
#define INVT  20.0f          // 1/TEMP
#define NEG_BIG -3.0e38f

typedef _Float16 half8  __attribute__((ext_vector_type(8)));
typedef _Float16 half4v __attribute__((ext_vector_type(4)));
typedef float    floatx4 __attribute__((ext_vector_type(4)));

// ---------------- block reduction helpers (1024 threads, wave64) ----------------
__device__ __forceinline__ float blockMax(float v, int tid, float* redW) {
#pragma unroll
  for (int off = 1; off < 64; off <<= 1) v = fmaxf(v, __shfl_xor(v, off));
  if ((tid & 63) == 0) redW[tid >> 6] = v;
  __syncthreads();
  float r = redW[0];
#pragma unroll
  for (int w = 1; w < NW; ++w) r = fmaxf(r, redW[w]);
  __syncthreads();
  return r;
}

__device__ __forceinline__ float blockSum(float v, int tid, float* redW) {
#pragma unroll
  for (int off = 1; off < 64; off <<= 1) v += __shfl_xor(v, off);
  if ((tid & 63) == 0) redW[tid >> 6] = v;
  __syncthreads();
  float r = 0.f;
#pragma unroll
  for (int w = 0; w < NW; ++w) r += redW[w];
  __syncthreads();
  return r;
}

// ---------------- exact k-th largest via 13-bit LDS histogram select ----------------
// getv(j): thread's j-th value (j in [0,32)). Bins by monotone key (sign-flip float).
// Usually 1 pass; refines (shift 19->6->0) only if the chosen bin holds >64 elems.
template <typename GetV>
__device__ __forceinline__ float histSelectK(GetV getv, int k, int tid,
                                             int* hist /*8192*/, int* wt /*NW*/,
                                             int* ibc /*4*/, float* bufV /*64*/,
                                             int* cntS, float* bcast) {
  const int lane = tid & 63, wid = tid >> 6;
  int shift = 19, prevShift = 32;
  unsigned prefix = 0;
  int krem = k;
  for (;;) {
    // zero histogram (8192 ints = 2048 int4)
    {
      int4* h4 = (int4*)hist;
      h4[tid] = make_int4(0, 0, 0, 0);
      h4[tid + 1024] = make_int4(0, 0, 0, 0);
    }
    __syncthreads();
    // histogram sweep
#pragma unroll
    for (int j = 0; j < 32; ++j) {
      float v = getv(j);
      unsigned bu = __float_as_uint(v);
      unsigned key = bu ^ ((unsigned)(((int)bu) >> 31) | 0x80000000u);
      bool ok = (prevShift >= 32) || ((key >> prevShift) == prefix);
      if (ok) atomicAdd(&hist[(key >> shift) & 8191], 1);
    }
    __syncthreads();
    // per-thread sum of its 8 bins (bin range [8*tid, 8*tid+8))
    int bcnt[8];
    int L = 0;
#pragma unroll
    for (int j = 0; j < 8; ++j) { bcnt[j] = hist[8 * tid + j]; L += bcnt[j]; }
    // suffix-inclusive scan over threads (descending): S = sum of L for lanes >= lane
    int S = L;
#pragma unroll
    for (int off = 1; off < 64; off <<= 1) {
      int y = __shfl_down(S, off);
      S += (lane + off < 64) ? y : 0;
    }
    if (lane == 0) wt[wid] = S;
    __syncthreads();
    int aboveW = 0;
    for (int w = wid + 1; w < NW; ++w) aboveW += wt[w];
    const int R = S + aboveW;        // count of elems in bins >= 8*tid
    const int aboveR = R - L;        // count strictly above this thread's bins
    if (aboveR < krem && krem <= R) {
      int above = aboveR;
      int bsel = -1, csel = 0;
#pragma unroll
      for (int j = 7; j >= 0; --j) {
        if (bsel < 0) {
          if (above + bcnt[j] >= krem) { bsel = 8 * tid + j; csel = bcnt[j]; }
          else above += bcnt[j];
        }
      }
      ibc[0] = bsel; ibc[1] = krem - above; ibc[2] = csel;
    }
    __syncthreads();
    const int bstar = ibc[0];
    krem = ibc[1];
    const int cntT = ibc[2];
    __syncthreads();
    const int gap = prevShift - shift;
    prefix = (prefix << gap) | ((unsigned)bstar & ((1u << gap) - 1u));
    prevShift = shift;
    if (cntT <= 64 || shift == 0) break;
    shift = (shift >= 13) ? (shift - 13) : 0;
  }
  // collect candidates of the final bin: (key >> prevShift) == prefix
  if (tid == 0) cntS[0] = 0;
  __syncthreads();
#pragma unroll
  for (int j = 0; j < 32; ++j) {
    float v = getv(j);
    unsigned bu = __float_as_uint(v);
    unsigned key = bu ^ ((unsigned)(((int)bu) >> 31) | 0x80000000u);
    if ((key >> prevShift) == prefix) {
      int p = atomicAdd(cntS, 1);
      if (p < 64) bufV[p] = v;
    }
  }
  __syncthreads();
  // wave 0: krem-th largest among candidates
  if (tid < 64) {
    int n = min(cntS[0], 64);
    float vl = (tid < n) ? bufV[tid] : NEG_BIG;
    float vkv = NEG_BIG;
    for (int it = 0; it < krem; ++it) {
      float wv = vl;
#pragma unroll
      for (int off = 1; off < 64; off <<= 1) wv = fmaxf(wv, __shfl_xor(wv, off));
      if (it == krem - 1) vkv = wv;
      unsigned long long m = __ballot(vl == wv);
      int fl = (int)__ffsll(m) - 1;
      if (tid == fl) vl = NEG_BIG;
    }
    if (tid == 0) bcast[0] = vkv;
  }
  __syncthreads();
  float r = bcast[0];
  __syncthreads();
  return r;
}

// ---------------- kernel 0: gather prx, build A' = [features; mem[prx]] ----------------
__global__ void prep_kernel(const float* __restrict__ features,
                            const int* __restrict__ targets,
                            const int* __restrict__ all_prx,
                            const float* __restrict__ mem,
                            float* __restrict__ A2,
                            int* __restrict__ prxArr) {
  const int b = blockIdx.x;
  const int k = threadIdx.x;
  const int t = targets[b];
  const int pr = all_prx[t];
  if (k == 0) prxArr[b] = pr;
  A2[b * D_DIM + k] = features[b * D_DIM + k];
  A2[(B_SZ + b) * D_DIM + k] = mem[(size_t)pr * D_DIM + k];
}

// ---------------- kernel 1: split-fp16 3-pass MFMA GEMM ----------------
__global__ __launch_bounds__(256) void gemm_mfma(const float* __restrict__ A,
                                                 const float* __restrict__ Bm,
                                                 float* __restrict__ Co) {
  __shared__ _Float16 Ah[128][32], Al[128][32], Bh[128][32], Bl[128][32];
  const int tid = threadIdx.x;
  const int lane = tid & 63;
  const int wid = tid >> 6;
  const int wr = wid >> 1, wc = wid & 1;     // 2x2 waves, 64x64 each
  const int orig = (blockIdx.x & 7) * 128 + (blockIdx.x >> 3);
  const int rowBase = (orig & 3) << 7;
  const int colBase = (orig >> 2) << 7;

  const int trow = tid >> 3;
  const int tseg = tid & 7;

  floatx4 acc[4][4];
#pragma unroll
  for (int i = 0; i < 4; ++i)
#pragma unroll
    for (int j = 0; j < 4; ++j) {
      acc[i][j][0] = 0.f; acc[i][j][1] = 0.f; acc[i][j][2] = 0.f; acc[i][j][3] = 0.f;
    }

  const int fr = lane & 15;
  const int kg = (lane >> 4) << 3;

  for (int step = 0; step < 8; ++step) {
    const int k0 = step << 5;
    float4 sa[4], sb[4];
#pragma unroll
    for (int p = 0; p < 4; ++p) {
      const int r = trow + (p << 5);
      sa[p] = *(const float4*)(A  + (size_t)(rowBase + r) * D_DIM + k0 + tseg * 4);
      sb[p] = *(const float4*)(Bm + (size_t)(colBase + r) * D_DIM + k0 + tseg * 4);
    }
    __syncthreads();
#pragma unroll
    for (int p = 0; p < 4; ++p) {
      const int r = trow + (p << 5);
      float4 v = sa[p];
      half4v h, l;
      h[0] = (_Float16)v.x; l[0] = (_Float16)(v.x - (float)h[0]);
      h[1] = (_Float16)v.y; l[1] = (_Float16)(v.y - (float)h[1]);
      h[2] = (_Float16)v.z; l[2] = (_Float16)(v.z - (float)h[2]);
      h[3] = (_Float16)v.w; l[3] = (_Float16)(v.w - (float)h[3]);
      *(half4v*)&Ah[r][tseg * 4] = h;
      *(half4v*)&Al[r][tseg * 4] = l;
      v = sb[p];
      h[0] = (_Float16)v.x; l[0] = (_Float16)(v.x - (float)h[0]);
      h[1] = (_Float16)v.y; l[1] = (_Float16)(v.y - (float)h[1]);
      h[2] = (_Float16)v.z; l[2] = (_Float16)(v.z - (float)h[2]);
      h[3] = (_Float16)v.w; l[3] = (_Float16)(v.w - (float)h[3]);
      *(half4v*)&Bh[r][tseg * 4] = h;
      *(half4v*)&Bl[r][tseg * 4] = l;
    }
    __syncthreads();
    half8 ah[4], al[4], bh[4], bl[4];
#pragma unroll
    for (int f = 0; f < 4; ++f) {
      ah[f] = *(const half8*)&Ah[wr * 64 + f * 16 + fr][kg];
      al[f] = *(const half8*)&Al[wr * 64 + f * 16 + fr][kg];
      bh[f] = *(const half8*)&Bh[wc * 64 + f * 16 + fr][kg];
      bl[f] = *(const half8*)&Bl[wc * 64 + f * 16 + fr][kg];
    }
#pragma unroll
    for (int fm = 0; fm < 4; ++fm)
#pragma unroll
      for (int fn = 0; fn < 4; ++fn) {
        acc[fm][fn] = __builtin_amdgcn_mfma_f32_16x16x32_f16(ah[fm], bh[fn], acc[fm][fn], 0, 0, 0);
        acc[fm][fn] = __builtin_amdgcn_mfma_f32_16x16x32_f16(ah[fm], bl[fn], acc[fm][fn], 0, 0, 0);
        acc[fm][fn] = __builtin_amdgcn_mfma_f32_16x16x32_f16(al[fm], bh[fn], acc[fm][fn], 0, 0, 0);
      }
  }
  const int rsub = (lane >> 4) << 2;
#pragma unroll
  for (int fm = 0; fm < 4; ++fm)
#pragma unroll
    for (int fn = 0; fn < 4; ++fn) {
      const int r0 = rowBase + wr * 64 + fm * 16 + rsub;
      const int c0 = colBase + wc * 64 + fn * 16 + fr;
#pragma unroll
      for (int r = 0; r < 4; ++r)
        Co[(size_t)(r0 + r) * P_CNT + c0] = acc[fm][fn][r];
    }
}

// ---------------- kernel 2: per-sample losses — register-resident row ----------------
// Thread owns elements p(j) = 4*tid + 4096*(j>>2) + (j&3), j in [0,32).
__global__ __launch_bounds__(NTHR) void persample(const float* __restrict__ OUT,
                                                  const int* __restrict__ cams,
                                                  const int* __restrict__ prxArr,
                                                  float* __restrict__ intraArr,
                                                  float* __restrict__ crossArr,
                                                  float* __restrict__ onlArr) {
  __shared__ int   hist[8192];     // 32 KiB histogram
  __shared__ int   wt[NW];
  __shared__ int   ibc[4];
  __shared__ float bufV[64];
  __shared__ int   bufI[32];
  __shared__ int   cntS[4];
  __shared__ float redW[NW];
  __shared__ float sv[64];
  __shared__ int   si[64];
  __shared__ float cvW[NW * 8];
  __shared__ int   ciW[NW * 8];
  __shared__ float mw[NW], sw[NW];
  __shared__ float bcast[2];

  const int b = blockIdx.x;
  const int tid = threadIdx.x;
  const int lane = tid & 63, wid = tid >> 6;
  const float* Srow = OUT + (size_t)b * P_CNT;
  const float* Mrow = OUT + (size_t)(B_SZ + b) * P_CNT;
  const int pr = prxArr[b];
  const int cam = cams[b];
  const int base4 = tid << 2;

  // ---- load score row into registers (coalesced float4) ----
  float s[32];
#pragma unroll
  for (int q = 0; q < 8; ++q) {
    float4 f = ((const float4*)Srow)[tid + (q << 10)];
    s[4 * q + 0] = f.x; s[4 * q + 1] = f.y; s[4 * q + 2] = f.z; s[4 * q + 3] = f.w;
  }
  float pmax = NEG_BIG;
#pragma unroll
  for (int j = 0; j < 32; ++j) pmax = fmaxf(pmax, s[j]);
  const float M = blockMax(pmax, tid, redW);

  // ---- intra: online LSE over {p : p%8==cam}; thread holds them iff parity matches ----
  {
    const bool mine = ((tid & 1) == (cam >> 2));
    const int cc = cam & 3;
    float im = NEG_BIG, is = 0.f;
    if (mine) {
#pragma unroll
      for (int q = 0; q < 8; ++q) {
        float v = (cc == 0) ? s[4 * q] : (cc == 1) ? s[4 * q + 1]
                : (cc == 2) ? s[4 * q + 2] : s[4 * q + 3];
        if (v <= im) is += expf((v - im) * INVT);
        else { is = is * expf((im - v) * INVT) + 1.f; im = v; }
      }
    }
#pragma unroll
    for (int off = 1; off < 64; off <<= 1) {
      float m2 = __shfl_xor(im, off);
      float s2 = __shfl_xor(is, off);
      float Mx = fmaxf(im, m2);
      is = is * expf((im - Mx) * INVT) + s2 * expf((m2 - Mx) * INVT);
      im = Mx;
    }
    if (lane == 0) { mw[wid] = im; sw[wid] = is; }
  }
  __syncthreads();
  if (tid == 0) {
    float m0 = mw[0], s0 = sw[0];
    for (int w = 1; w < NW; ++w) {
      float Mx = fmaxf(m0, mw[w]);
      s0 = s0 * expf((m0 - Mx) * INVT) + sw[w] * expf((mw[w] - Mx) * INVT);
      m0 = Mx;
    }
    intraArr[b] = -((Srow[pr] - m0) * INVT - logf(s0));
  }

  // ---- cross: exclude pos=[posBase..+8); exact 50th of rest; LSE ----
  const int posBase = pr & ~7;
  if (tid < 8) sv[tid] = Srow[posBase + tid];
  __syncthreads();
  auto crossVal = [&](int j) -> float {
    int p = base4 + ((j >> 2) << 12) + (j & 3);
    return ((unsigned)(p - posBase) < 8u) ? NEG_BIG : s[j];
  };
  const float vk = histSelectK(crossVal, 50, tid, hist, wt, ibc, bufV, cntS, bcast);
  {
    float se = 0.f, cg = 0.f;
#pragma unroll
    for (int j = 0; j < 32; ++j) {
      float v = crossVal(j);
      if (v > vk) { se += expf((v - M) * INVT); cg += 1.f; }
    }
    se = blockSum(se, tid, redW);
    cg = blockSum(cg, tid, redW);
    if (tid == 0) {
      float stot = se + (50.f - cg) * expf((vk - M) * INVT);
      for (int p = 0; p < 8; ++p) stot += expf((sv[p] - M) * INVT);
      float lse = logf(stot);
      float acc = 0.f;
      for (int p = 0; p < 8; ++p) acc += (sv[p] - M) * INVT - lse;
      crossArr[b] = -acc * 0.125f;
    }
  }

  // ---- sims in place: s := 0.15*score + 0.85*memsim ----
#pragma unroll
  for (int q = 0; q < 8; ++q) {
    float4 m2 = ((const float4*)Mrow)[tid + (q << 10)];
    s[4 * q + 0] = 0.15f * s[4 * q + 0] + 0.85f * m2.x;
    s[4 * q + 1] = 0.15f * s[4 * q + 1] + 0.85f * m2.y;
    s[4 * q + 2] = 0.15f * s[4 * q + 2] + 0.85f * m2.z;
    s[4 * q + 3] = 0.15f * s[4 * q + 3] + 0.85f * m2.w;
  }

  // ---- per-camera argmax: thread parity covers 4 of 8 cameras ----
  {
    float cm[4] = {NEG_BIG, NEG_BIG, NEG_BIG, NEG_BIG};
    int cix[4] = {0x7fffffff, 0x7fffffff, 0x7fffffff, 0x7fffffff};
#pragma unroll
    for (int q = 0; q < 8; ++q) {
#pragma unroll
      for (int c = 0; c < 4; ++c) {
        float v = s[4 * q + c];
        int p = base4 + (q << 12) + c;
        if (v > cm[c]) { cm[c] = v; cix[c] = p; }
      }
    }
    const bool odd = (tid & 1);
    float v8[8]; int i8[8];
#pragma unroll
    for (int c = 0; c < 4; ++c) {
      float ov = __shfl_xor(cm[c], 1); int oi = __shfl_xor(cix[c], 1);
      v8[c]     = odd ? ov : cm[c];   i8[c]     = odd ? oi : cix[c];
      v8[c + 4] = odd ? cm[c] : ov;   i8[c + 4] = odd ? cix[c] : oi;
    }
#pragma unroll
    for (int off = 2; off <= 32; off <<= 1) {
#pragma unroll
      for (int c = 0; c < 8; ++c) {
        float vv = __shfl_xor(v8[c], off);
        int   ii = __shfl_xor(i8[c], off);
        if (vv > v8[c] || (vv == v8[c] && ii < i8[c])) { v8[c] = vv; i8[c] = ii; }
      }
    }
    if (lane < 8) {
#pragma unroll
      for (int c = 0; c < 8; ++c)
        if (lane == c) { cvW[wid * 8 + c] = v8[c]; ciW[wid * 8 + c] = i8[c]; }
    }
    __syncthreads();
    if (tid < 8) {
      float v = cvW[tid]; int ix = ciW[tid];
      for (int w = 1; w < NW; ++w) {
        float v2 = cvW[w * 8 + tid]; int i2 = ciW[w * 8 + tid];
        if (v2 > v || (v2 == v && i2 < ix)) { v = v2; ix = i2; }
      }
      cvW[tid] = v; ciW[tid] = ix;
    }
    __syncthreads();
    if (tid == 0) {
      unsigned used = 0;
      for (int k = 0; k < 3; ++k) {
        float best = NEG_BIG; int bc = 0;
        for (int c = 0; c < 8; ++c)
          if (!((used >> c) & 1u) && cvW[c] > best) { best = cvW[c]; bc = c; }
        used |= 1u << bc;
        si[k] = ciW[bc];
      }
    }
    __syncthreads();
  }
  const int c0 = si[0], c1 = si[1], c2 = si[2];
  __syncthreads();

  // ---- online: exclude chosen; exact 50th of rest; collect indices ----
  auto simsVal = [&](int j) -> float {
    int p = base4 + ((j >> 2) << 12) + (j & 3);
    return (p == c0 || p == c1 || p == c2) ? NEG_BIG : s[j];
  };
  const float vk2 = histSelectK(simsVal, 50, tid, hist, wt, ibc, bufV, cntS, bcast);
  if (tid == 0) { cntS[1] = 0; cntS[2] = 0; }
  __syncthreads();
#pragma unroll
  for (int j = 0; j < 32; ++j) {
    float v = simsVal(j);
    int p = base4 + ((j >> 2) << 12) + (j & 3);
    if (v > vk2) {
      int t = atomicAdd(&cntS[1], 1);
      if (t < 50) si[3 + t] = p;
    } else if (v == vk2) {
      int t = atomicAdd(&cntS[2], 1);
      if (t < 32) bufI[t] = p;
    }
  }
  __syncthreads();
  {
    const int cg = cntS[1];
    const int fill = 50 - cg;
    if (tid < 64) {
      int ne = min(cntS[2], 32);
      int il = (tid < ne) ? bufI[tid] : 0x7fffffff;
      for (int it = 0; it < fill; ++it) {
        int wi = il;
#pragma unroll
        for (int off = 1; off < 64; off <<= 1) wi = min(wi, __shfl_xor(wi, off));
        if (tid == 0) si[3 + cg + it] = wi;
        if (il == wi) il = 0x7fffffff;
      }
    }
  }
  __syncthreads();
  if (tid < 53) sv[tid] = Srow[si[tid]];   // gather scores at selected indices (L2-hot)
  __syncthreads();
  if (tid < 64) {
    float v = (tid < 53) ? sv[tid] : NEG_BIG;
    float mm = v;
#pragma unroll
    for (int off = 1; off < 64; off <<= 1) mm = fmaxf(mm, __shfl_xor(mm, off));
    float e = (tid < 53) ? expf((v - mm) * INVT) : 0.f;
    float ss = e;
#pragma unroll
    for (int off = 1; off < 64; off <<= 1) ss += __shfl_xor(ss, off);
    float lse = logf(ss);
    float c = (tid < 3) ? ((v - mm) * INVT - lse) : 0.f;
#pragma unroll
    for (int off = 1; off < 64; off <<= 1) c += __shfl_xor(c, off);
    if (tid == 0) onlArr[b] = -c * (1.0f / 3.0f);
  }
}

// ---------------- kernel 3: per-camera means -> scalar ----------------
__global__ void finalize(const int* __restrict__ cams,
                         const float* __restrict__ ia,
                         const float* __restrict__ ca,
                         const float* __restrict__ oa,
                         float* __restrict__ out) {
  if (blockIdx.x == 0 && threadIdx.x == 0) {
    float s[8] = {}; float n[8] = {};
    for (int b = 0; b < B_SZ; ++b) {
      int c = cams[b];
      s[c] += ia[b] + ca[b] + oa[b];
      n[c] += 1.f;
    }
    float tot = 0.f;
    for (int c = 0; c < 8; ++c)
      if (n[c] > 0.f) tot += s[c] / n[c];
    out[0] = tot;
  }
}

extern "C" void kernel_launch(void* const* d_in, const int* in_sizes, int n_in,
                              void* d_out, int out_size, void* d_ws, size_t ws_size,
                              hipStream_t stream) {
  const float* features = (const float*)d_in[0];
  const int*   targets  = (const int*)d_in[1];
  const int*   cams     = (const int*)d_in[2];
  const float* mem      = (const float*)d_in[4];
  const int*   all_prx  = (const int*)d_in[6];

  float* ws = (float*)d_ws;
  float* A2  = ws;                               // 512*256
  float* OUT = ws + 512 * D_DIM;                 // 512*32768
  float* tail = OUT + (size_t)512 * P_CNT;
  int*   prxArr  = (int*)tail;                   // 256
  float* intraArr = (float*)(prxArr + B_SZ);     // 256
  float* crossArr = intraArr + B_SZ;             // 256
  float* onlArr   = crossArr + B_SZ;             // 256

  prep_kernel<<<B_SZ, D_DIM, 0, stream>>>(features, targets, all_prx, mem, A2, prxArr);
  gemm_mfma<<<1024, 256, 0, stream>>>(A2, mem, OUT);
  persample<<<B_SZ, NTHR, 0, stream>>>(OUT, cams, prxArr, intraArr, crossArr, onlArr);
  finalize<<<1, 64, 0, stream>>>(cams, intraArr, crossArr, onlArr, (float*)d_out);
}